// Round 13
// baseline (310.742 us; speedup 1.0000x reference)
//
#include <hip/hip_runtime.h>

#define HIDDEN 64

typedef float f32x4 __attribute__((ext_vector_type(4)));
typedef short bf16x8 __attribute__((ext_vector_type(8)));
typedef unsigned int u32x4 __attribute__((ext_vector_type(4)));

union U8 {
    bf16x8 v;
    unsigned short s[8];
    unsigned int d[4];
};

__device__ __forceinline__ float lane_bcast(float v, int l) {
    return __uint_as_float(__builtin_amdgcn_readlane(__float_as_uint(v), l));
}

// bf16 round-to-nearest-even pack; cheap unpacks of a packed pair
__device__ __forceinline__ unsigned int f2b(float f) {
    unsigned int u = __float_as_uint(f);
    return (u + 0x7FFFu + ((u >> 16) & 1u)) >> 16;
}
__device__ __forceinline__ float b2f(unsigned int v) {
    return __uint_as_float(v << 16);
}
__device__ __forceinline__ float blo(unsigned int v) {
    return __uint_as_float(v << 16);
}
__device__ __forceinline__ float bhi(unsigned int v) {
    return __uint_as_float(v & 0xFFFF0000u);
}

__device__ __forceinline__ int grp_of(int dst, int N) {
    return (int)((8LL * dst) / N);
}

// =====================  prep: xcvt + block-chunk group counts + per-dst hist  =======
__global__ __launch_bounds__(256) void prep_kernel(const float4* __restrict__ x,
                                                   ushort4* __restrict__ x16, int n4,
                                                   const int* __restrict__ ei,
                                                   int* __restrict__ cnt,
                                                   int* __restrict__ blkcnt,
                                                   int E, int C, int N) {
    __shared__ int gh[8];
    const int tid = threadIdx.x;
    const int st = gridDim.x * blockDim.x;
    for (int i = blockIdx.x * blockDim.x + tid; i < n4; i += st) {
        const float4 v = x[i];
        ushort4 o;
        o.x = (unsigned short)f2b(v.x);
        o.y = (unsigned short)f2b(v.y);
        o.z = (unsigned short)f2b(v.z);
        o.w = (unsigned short)f2b(v.w);
        x16[i] = o;
    }
    if (tid < 8) gh[tid] = 0;
    __syncthreads();
    const int e0 = blockIdx.x * C;
    const int e1 = min(e0 + C, E);
    for (int i = e0 + tid; i < e1; i += 256) {
        const int dst = __builtin_nontemporal_load(&ei[E + i]);
        atomicAdd(&gh[grp_of(dst, N)], 1);
        atomicAdd(&cnt[dst], 1);
    }
    __syncthreads();
    if (tid < 8) blkcnt[blockIdx.x * 8 + tid] = gh[tid];
}

// =====================  qscan: (g,b)-order exclusive scan of blkcnt -> qoff  ========
// One block. qoff[b*8+g] = group-major queue offset for block b's group-g run.
// qoff[0*8+g] doubles as the group-g base (b=0 is first in each group).
__global__ __launch_bounds__(256) void qscan_kernel(const int* __restrict__ blkcnt,
                                                    int* __restrict__ qoff, int nblk) {
    __shared__ int s[256];
    __shared__ int carry;
    const int t = threadIdx.x;
    if (t == 0) carry = 0;
    __syncthreads();
    for (int g = 0; g < 8; ++g) {
        for (int base = 0; base < nblk; base += 256) {
            const int b = base + t;
            const int v = (b < nblk) ? blkcnt[b * 8 + g] : 0;
            s[t] = v;
            __syncthreads();
            for (int d = 1; d < 256; d <<= 1) {
                int u = (t >= d) ? s[t - d] : 0;
                __syncthreads();
                s[t] += u;
                __syncthreads();
            }
            const int c = carry;
            if (b < nblk) qoff[b * 8 + g] = c + s[t] - v;
            __syncthreads();
            if (t == 0) carry = c + s[255];
            __syncthreads();
        }
    }
}

// =====================  scans over per-dst cnt -> off (in place)  =====================
__global__ __launch_bounds__(256) void scan1_kernel(int* __restrict__ cnt, int* __restrict__ partial,
                                                    int N) {
    __shared__ int s[256];
    const int t = threadIdx.x;
    const int base = blockIdx.x * 1024 + t * 4;
    int v0 = (base + 0 < N) ? cnt[base + 0] : 0;
    int v1 = (base + 1 < N) ? cnt[base + 1] : 0;
    int v2 = (base + 2 < N) ? cnt[base + 2] : 0;
    int v3 = (base + 3 < N) ? cnt[base + 3] : 0;
    const int mysum = v0 + v1 + v2 + v3;
    s[t] = mysum;
    __syncthreads();
    for (int d = 1; d < 256; d <<= 1) {
        int u = (t >= d) ? s[t - d] : 0;
        __syncthreads();
        s[t] += u;
        __syncthreads();
    }
    const int excl = s[t] - mysum;
    if (base + 0 < N) cnt[base + 0] = excl;
    if (base + 1 < N) cnt[base + 1] = excl + v0;
    if (base + 2 < N) cnt[base + 2] = excl + v0 + v1;
    if (base + 3 < N) cnt[base + 3] = excl + v0 + v1 + v2;
    if (t == 255) partial[blockIdx.x] = s[255];
}

__global__ __launch_bounds__(256) void scan2_kernel(int* __restrict__ partial, int nb) {
    __shared__ int s[256];
    const int t = threadIdx.x;
    const int mysum = (t < nb) ? partial[t] : 0;
    s[t] = mysum;
    __syncthreads();
    for (int d = 1; d < 256; d <<= 1) {
        int u = (t >= d) ? s[t - d] : 0;
        __syncthreads();
        s[t] += u;
        __syncthreads();
    }
    if (t < nb) partial[t] = s[t] - mysum;
}

__global__ __launch_bounds__(256) void scan3_kernel(int* __restrict__ off,
                                                    const int* __restrict__ partial, int N, int E) {
    int i = blockIdx.x * blockDim.x + threadIdx.x;
    if (i < N) off[i] += partial[i >> 10];
    if (i == 0) off[N] = E;
}

// =====================  qwrite: dense per-block runs into group-major queue  ========
// Each block re-reads its chunk once (NT) and appends {src,dst,ea-bf16} into its
// 8 reserved runs via LDS cursors (no global atomics). Runs are ~KB-sized and
// written within a tight window -> full-line write-combining by construction.
__global__ __launch_bounds__(256) void qwrite_kernel(const int* __restrict__ ei,
                                                     const float* __restrict__ ea,
                                                     const int* __restrict__ qoff,
                                                     u32x4* __restrict__ queue,
                                                     int E, int C, int N) {
    __shared__ int lcur[8];
    const int tid = threadIdx.x;
    if (tid < 8) lcur[tid] = qoff[blockIdx.x * 8 + tid];
    __syncthreads();
    const int e0 = blockIdx.x * C;
    const int e1 = min(e0 + C, E);
    for (int i = e0 + tid; i < e1; i += 256) {
        const int dst = __builtin_nontemporal_load(&ei[E + i]);
        const int src = __builtin_nontemporal_load(&ei[i]);
        const f32x4 a = __builtin_nontemporal_load((const f32x4*)&ea[(size_t)i * 4]);
        const int g = grp_of(dst, N);
        const int pos = atomicAdd(&lcur[g], 1);
        u32x4 q;
        q.x = (unsigned int)src;
        q.y = (unsigned int)dst;
        q.z = f2b(a.x) | (f2b(a.y) << 16);
        q.w = f2b(a.z) | (f2b(a.w) << 16);
        queue[pos] = q;
    }
}

// =====================  scatter2: stream own group's queue slice -> per-dst recs  ===
// Group g = blockIdx&7 reads ONLY its contiguous queue slice (sequential, once).
// Slot via atomicAdd on off[dst] directly (off-shift trick: afterwards
// off[n] == original off[n+1]). recs region per group = 3.2 MB, XCD-local.
__global__ __launch_bounds__(256) void scatter2_kernel(const u32x4* __restrict__ queue,
                                                       const int* __restrict__ qoff,
                                                       int* __restrict__ off,
                                                       u32x4* __restrict__ recs, int E) {
    const int g = blockIdx.x & 7;
    const int gblk = blockIdx.x >> 3;
    const int nblk = gridDim.x >> 3;
    const int q0 = qoff[g];                       // b=0 entries are group bases
    const int q1 = (g < 7) ? qoff[g + 1] : E;
    for (int i = q0 + gblk * (int)blockDim.x + (int)threadIdx.x; i < q1;
         i += nblk * (int)blockDim.x) {
        const u32x4 q = __builtin_nontemporal_load(&queue[i]);
        const int slot = atomicAdd(&off[(int)q.y], 1);
        u32x4 r;
        r.x = q.x;
        r.y = q.z;
        r.z = q.w;
        r.w = 0u;
        recs[slot] = r;  // plain store: write-combines in this XCD's L2
    }
}

// =====================  gather (XCD-grouped nodes, shifted-off bounds)  =============
__global__ __launch_bounds__(256) void gather16_kernel(
    const float* __restrict__ x, const unsigned short* __restrict__ x16,
    const int* __restrict__ off, const u32x4* __restrict__ recs,
    const float* __restrict__ We, const float* __restrict__ be, float* __restrict__ hout, int N) {
    const int lane = threadIdx.x & 63;
    const float w0 = We[lane];
    const float w1 = We[64 + lane];
    const float w2 = We[128 + lane];
    const float w3 = We[192 + lane];
    const float bb = be[lane];
    const int g = blockIdx.x & 7;
    const int gblk = blockIdx.x >> 3;
    const int nblk = gridDim.x >> 3;
    const int lo = (int)(((long long)g * N + 7) / 8);
    const int hi = (int)(((long long)(g + 1) * N + 7) / 8);
    int wave = (gblk * (int)blockDim.x + (int)threadIdx.x) >> 6;
    const int nw = (nblk * (int)blockDim.x) >> 6;
    for (int n = lo + wave; n < hi; n += nw) {
        // post-scatter2: off[n] == original off[n+1]
        const int s0 = __builtin_amdgcn_readfirstlane(n == 0 ? 0 : off[n - 1]);
        const int s1 = __builtin_amdgcn_readfirstlane(off[n]);
        float acc = x[(size_t)n * HIDDEN + lane];
        int s = s0;
        for (; s + 4 <= s1; s += 4) {
            const u32x4 r0 = recs[s + 0];
            const u32x4 r1 = recs[s + 1];
            const u32x4 r2 = recs[s + 2];
            const u32x4 r3 = recs[s + 3];
            const float x0 = b2f(x16[(size_t)r0.x * HIDDEN + lane]);
            const float x1 = b2f(x16[(size_t)r1.x * HIDDEN + lane]);
            const float x2 = b2f(x16[(size_t)r2.x * HIDDEN + lane]);
            const float x3 = b2f(x16[(size_t)r3.x * HIDDEN + lane]);
            const float p0 = fmaf(bhi(r0.z), w3, fmaf(blo(r0.z), w2,
                             fmaf(bhi(r0.y), w1, fmaf(blo(r0.y), w0, bb))));
            const float p1 = fmaf(bhi(r1.z), w3, fmaf(blo(r1.z), w2,
                             fmaf(bhi(r1.y), w1, fmaf(blo(r1.y), w0, bb))));
            const float p2 = fmaf(bhi(r2.z), w3, fmaf(blo(r2.z), w2,
                             fmaf(bhi(r2.y), w1, fmaf(blo(r2.y), w0, bb))));
            const float p3 = fmaf(bhi(r3.z), w3, fmaf(blo(r3.z), w2,
                             fmaf(bhi(r3.y), w1, fmaf(blo(r3.y), w0, bb))));
            acc += fmaxf(x0 + p0, 0.0f);
            acc += fmaxf(x1 + p1, 0.0f);
            acc += fmaxf(x2 + p2, 0.0f);
            acc += fmaxf(x3 + p3, 0.0f);
        }
        for (; s < s1; ++s) {
            const u32x4 r = recs[s];
            const float xv = b2f(x16[(size_t)r.x * HIDDEN + lane]);
            const float p = fmaf(bhi(r.z), w3, fmaf(blo(r.z), w2,
                            fmaf(bhi(r.y), w1, fmaf(blo(r.y), w0, bb))));
            acc += fmaxf(xv + p, 0.0f);
        }
        hout[(size_t)n * HIDDEN + lane] = acc;
    }
}

// =====================  MLP via MFMA (LDS-staged W, grid-stride; verified)  =========
__global__ __launch_bounds__(256) void mlp_mfma_kernel(float* __restrict__ hio,
                                                       const float* __restrict__ W1,
                                                       const float* __restrict__ b1,
                                                       const float* __restrict__ W2,
                                                       const float* __restrict__ b2, int N) {
    __shared__ unsigned short w1s[4096], w2s[4096];
    __shared__ unsigned short tlds[4][16 * 72];
    const int tid = threadIdx.x;
    const int lane = tid & 63;
    const int wid = tid >> 6;
    const int g = lane >> 4;
    const int c = lane & 15;

    for (int i = tid; i < 4096; i += 256) {
        w1s[i] = (unsigned short)f2b(W1[i]);
        w2s[i] = (unsigned short)f2b(W2[i]);
    }
    __syncthreads();

    U8 a1[4][2], a2[4][2];
#pragma unroll
    for (int ct = 0; ct < 4; ++ct)
#pragma unroll
        for (int kk = 0; kk < 2; ++kk)
#pragma unroll
            for (int j = 0; j < 8; ++j) {
                a1[ct][kk].s[j] = w1s[(kk * 32 + g * 8 + j) * 64 + ct * 16 + c];
                a2[ct][kk].s[j] = w2s[(kk * 32 + g * 8 + j) * 64 + ct * 16 + c];
            }
    float b1c[4][4], b2c[4][4];
#pragma unroll
    for (int ct = 0; ct < 4; ++ct)
#pragma unroll
        for (int r = 0; r < 4; ++r) {
            b1c[ct][r] = b1[ct * 16 + g * 4 + r];
            b2c[ct][r] = b2[ct * 16 + g * 4 + r];
        }

    unsigned char* myb = (unsigned char*)&tlds[wid][0];
    const int ntiles = (N + 15) >> 4;

    for (int tile = blockIdx.x * 4 + wid; tile < ntiles; tile += gridDim.x * 4) {
        const int row = tile * 16 + c;
        const int rowc = min(row, N - 1);

        U8 b1f[2];
#pragma unroll
        for (int kk = 0; kk < 2; ++kk) {
            const float4* hp = (const float4*)&hio[(size_t)rowc * 64 + kk * 32 + g * 8];
            const float4 lo = hp[0];
            const float4 hi = hp[1];
            b1f[kk].d[0] = f2b(lo.x) | (f2b(lo.y) << 16);
            b1f[kk].d[1] = f2b(lo.z) | (f2b(lo.w) << 16);
            b1f[kk].d[2] = f2b(hi.x) | (f2b(hi.y) << 16);
            b1f[kk].d[3] = f2b(hi.z) | (f2b(hi.w) << 16);
        }
        f32x4 acc1[4];
#pragma unroll
        for (int ct = 0; ct < 4; ++ct) {
            acc1[ct] = (f32x4)(0.0f);
#pragma unroll
            for (int kk = 0; kk < 2; ++kk)
                acc1[ct] = __builtin_amdgcn_mfma_f32_16x16x32_bf16(a1[ct][kk].v, b1f[kk].v,
                                                                   acc1[ct], 0, 0, 0);
        }
#pragma unroll
        for (int ct = 0; ct < 4; ++ct)
#pragma unroll
            for (int rp = 0; rp < 2; ++rp) {
                const float v0 = fmaxf(acc1[ct][2 * rp + 0] + b1c[ct][2 * rp + 0], 0.0f);
                const float v1 = fmaxf(acc1[ct][2 * rp + 1] + b1c[ct][2 * rp + 1], 0.0f);
                *(unsigned int*)(myb + c * 144 + ct * 32 + g * 8 + rp * 4) =
                    f2b(v0) | (f2b(v1) << 16);
            }
        U8 b2f_[2];
#pragma unroll
        for (int kk2 = 0; kk2 < 2; ++kk2) {
            const unsigned int* q = (const unsigned int*)(myb + c * 144 + kk2 * 64 + g * 16);
            b2f_[kk2].d[0] = q[0];
            b2f_[kk2].d[1] = q[1];
            b2f_[kk2].d[2] = q[2];
            b2f_[kk2].d[3] = q[3];
        }
        f32x4 acc2[4];
#pragma unroll
        for (int ct = 0; ct < 4; ++ct) {
            acc2[ct] = (f32x4)(0.0f);
#pragma unroll
            for (int kk2 = 0; kk2 < 2; ++kk2)
                acc2[ct] = __builtin_amdgcn_mfma_f32_16x16x32_bf16(a2[ct][kk2].v, b2f_[kk2].v,
                                                                   acc2[ct], 0, 0, 0);
        }
        if (row < N) {
#pragma unroll
            for (int ct = 0; ct < 4; ++ct)
#pragma unroll
                for (int r = 0; r < 4; ++r)
                    hio[(size_t)row * 64 + ct * 16 + g * 4 + r] = acc2[ct][r] + b2c[ct][r];
        }
    }
}

// =====================  fallback path (ws too small)  =====================
__global__ __launch_bounds__(256) void mlp_kernel(const float* __restrict__ hin,
                                                  const float* __restrict__ W1,
                                                  const float* __restrict__ b1,
                                                  const float* __restrict__ W2,
                                                  const float* __restrict__ b2,
                                                  float* __restrict__ out, int N) {
    const int lane = threadIdx.x & 63;
    float w1c[64], w2c[64];
#pragma unroll
    for (int k = 0; k < 64; ++k) w1c[k] = W1[k * 64 + lane];
#pragma unroll
    for (int k = 0; k < 64; ++k) w2c[k] = W2[k * 64 + lane];
    const float bb1 = b1[lane];
    const float bb2 = b2[lane];
    int wave = (blockIdx.x * blockDim.x + threadIdx.x) >> 6;
    const int nw = (gridDim.x * blockDim.x) >> 6;
    for (int n = wave; n < N; n += nw) {
        const float h = hin[(size_t)n * HIDDEN + lane];
        float t0 = bb1, t1 = 0.0f;
#pragma unroll
        for (int k = 0; k < 64; k += 2) {
            t0 = fmaf(lane_bcast(h, k), w1c[k], t0);
            t1 = fmaf(lane_bcast(h, k + 1), w1c[k + 1], t1);
        }
        const float t = fmaxf(t0 + t1, 0.0f);
        float o0 = bb2, o1 = 0.0f;
#pragma unroll
        for (int k = 0; k < 64; k += 2) {
            o0 = fmaf(lane_bcast(t, k), w2c[k], o0);
            o1 = fmaf(lane_bcast(t, k + 1), w2c[k + 1], o1);
        }
        out[(size_t)n * HIDDEN + lane] = o0 + o1;
    }
}

__global__ __launch_bounds__(256) void gine_copy_kernel(const float4* __restrict__ x,
                                                        float4* __restrict__ out, int n4) {
    int i = blockIdx.x * blockDim.x + threadIdx.x;
    int stride = gridDim.x * blockDim.x;
    for (; i < n4; i += stride) out[i] = x[i];
}

__global__ __launch_bounds__(256) void gine_edge_kernel(const float* __restrict__ x,
                                                        const int* __restrict__ ei,
                                                        const float4* __restrict__ ea,
                                                        const float* __restrict__ We,
                                                        const float* __restrict__ be,
                                                        float* __restrict__ out, int E) {
    const int lane = threadIdx.x & 63;
    const float w0 = We[lane];
    const float w1 = We[64 + lane];
    const float w2 = We[128 + lane];
    const float w3 = We[192 + lane];
    const float bb = be[lane];
    int wave = (blockIdx.x * blockDim.x + threadIdx.x) >> 6;
    const int nw = (gridDim.x * blockDim.x) >> 6;
    for (int e = wave; e < E; e += nw) {
        const int src = ei[e];
        const int dst = ei[E + e];
        const float4 a = ea[e];
        float m = x[src * HIDDEN + lane] + (bb + a.x * w0 + a.y * w1 + a.z * w2 + a.w * w3);
        m = fmaxf(m, 0.0f);
        atomicAdd(out + dst * HIDDEN + lane, m);
    }
}

extern "C" void kernel_launch(void* const* d_in, const int* in_sizes, int n_in,
                              void* d_out, int out_size, void* d_ws, size_t ws_size,
                              hipStream_t stream) {
    const float* x  = (const float*)d_in[0];
    const int*   ei = (const int*)d_in[1];
    const float* ea = (const float*)d_in[2];
    const float* We = (const float*)d_in[3];
    const float* be = (const float*)d_in[4];
    const float* W1 = (const float*)d_in[5];
    const float* b1 = (const float*)d_in[6];
    const float* W2 = (const float*)d_in[7];
    const float* b2 = (const float*)d_in[8];
    float* out = (float*)d_out;

    const int N = in_sizes[0] / HIDDEN;  // 100000
    const int E = in_sizes[1] / 2;       // 1600000
    const int NBLK = 2048;
    const int C = (E + NBLK - 1) / NBLK;  // edges per block chunk

    // Workspace layout; the 25.6 MB group-major queue lives in d_out (dead
    // before gather overwrites d_out with h). E*16 == out bytes exactly here;
    // fall back if it wouldn't fit.
    const size_t off_bytes = (size_t)(N + 1) * 4;
    size_t p = 0;
    const size_t off_ofs   = p; p += (off_bytes + 255) & ~(size_t)255;
    const size_t part_ofs  = p; p += 512 * 4;
    const size_t blk_ofs   = p; p += (size_t)NBLK * 8 * 4;
    const size_t qoff_ofs  = p; p += (size_t)NBLK * 8 * 4;
    const size_t rec_ofs   = p; p += (size_t)E * 16;
    const size_t x16_ofs   = p; p += ((size_t)N * HIDDEN * 2 + 255) & ~(size_t)255;
    const size_t need = p;
    const bool queue_fits = (size_t)E * 16 <= (size_t)out_size * 4;

    if (ws_size < need || !queue_fits) {
        gine_copy_kernel<<<2048, 256, 0, stream>>>((const float4*)x, (float4*)out,
                                                   N * (HIDDEN / 4));
        gine_edge_kernel<<<2048, 256, 0, stream>>>(x, ei, (const float4*)ea, We, be, out, E);
        mlp_kernel<<<2048, 256, 0, stream>>>(out, W1, b1, W2, b2, out, N);
        return;
    }

    char* ws = (char*)d_ws;
    int*            off    = (int*)(ws + off_ofs);
    int*            part   = (int*)(ws + part_ofs);
    int*            blkcnt = (int*)(ws + blk_ofs);
    int*            qoff   = (int*)(ws + qoff_ofs);
    u32x4*          recs   = (u32x4*)(ws + rec_ofs);
    unsigned short* x16    = (unsigned short*)(ws + x16_ofs);
    u32x4*          queue  = (u32x4*)d_out;

    const int nb_scan = (N + 1023) / 1024;  // <= 256 for N <= 262144

    hipMemsetAsync(off, 0, off_bytes, stream);
    prep_kernel<<<NBLK, 256, 0, stream>>>((const float4*)x, (ushort4*)x16, N * (HIDDEN / 4),
                                          ei, off, blkcnt, E, C, N);
    qscan_kernel<<<1, 256, 0, stream>>>(blkcnt, qoff, NBLK);
    scan1_kernel<<<nb_scan, 256, 0, stream>>>(off, part, N);
    scan2_kernel<<<1, 256, 0, stream>>>(part, nb_scan);
    scan3_kernel<<<(N + 255) / 256, 256, 0, stream>>>(off, part, N, E);
    qwrite_kernel<<<NBLK, 256, 0, stream>>>(ei, ea, qoff, queue, E, C, N);
    scatter2_kernel<<<2048, 256, 0, stream>>>(queue, qoff, off, recs, E);
    gather16_kernel<<<2048, 256, 0, stream>>>(x, x16, off, recs, We, be, out, N);
    mlp_mfma_kernel<<<640, 256, 0, stream>>>(out, W1, b1, W2, b2, N);
}

// Round 14
// 173.157 us; speedup vs baseline: 1.7946x; 1.7946x over previous
//
#include <hip/hip_runtime.h>

#define HIDDEN 64
#define NCHUNK 512
#define CMAX 3200      // max edges per chunk supported by qsort LDS
#define NBMAX 1568     // max buckets supported by qsort LDS
#define CAP 1536       // bgather staging capacity (Poisson mean 1024, +16 sigma)

typedef float f32x4 __attribute__((ext_vector_type(4)));
typedef short bf16x8 __attribute__((ext_vector_type(8)));
typedef unsigned int u32x4 __attribute__((ext_vector_type(4)));

union U8 {
    bf16x8 v;
    unsigned short s[8];
    unsigned int d[4];
};

__device__ __forceinline__ float lane_bcast(float v, int l) {
    return __uint_as_float(__builtin_amdgcn_readlane(__float_as_uint(v), l));
}
__device__ __forceinline__ unsigned int f2b(float f) {
    unsigned int u = __float_as_uint(f);
    return (u + 0x7FFFu + ((u >> 16) & 1u)) >> 16;
}
__device__ __forceinline__ float b2f(unsigned int v) { return __uint_as_float(v << 16); }
__device__ __forceinline__ float blo(unsigned int v) { return __uint_as_float(v << 16); }
__device__ __forceinline__ float bhi(unsigned int v) { return __uint_as_float(v & 0xFFFF0000u); }

// =====================  qsort: chunk-local bucket sort, all writes coalesced  =======
// Block c: count 64-node-bucket bins over its chunk, LDS-scan, place 12B records
// sorted-by-bucket in LDS, write chunk contiguously + tab[c][b]={roff:16|cnt:16}.
// Also fused: x -> bf16 convert (independent streaming work).
__global__ __launch_bounds__(256) void qsort_kernel(const float4* __restrict__ x,
                                                    ushort4* __restrict__ x16, int n4,
                                                    const int* __restrict__ ei,
                                                    const float* __restrict__ ea,
                                                    unsigned int* __restrict__ queue,
                                                    unsigned int* __restrict__ tab,
                                                    int E, int C, int NB) {
    __shared__ unsigned int srec[3 * CMAX];  // 38.4 KB
    __shared__ int cnt[NBMAX];               // 6.3 KB
    __shared__ int s[256];
    __shared__ int carry;
    const int tid = threadIdx.x;

    // fused xcvt
    for (int i = blockIdx.x * blockDim.x + tid; i < n4; i += gridDim.x * blockDim.x) {
        const float4 v = x[i];
        ushort4 o;
        o.x = (unsigned short)f2b(v.x);
        o.y = (unsigned short)f2b(v.y);
        o.z = (unsigned short)f2b(v.z);
        o.w = (unsigned short)f2b(v.w);
        x16[i] = o;
    }

    const int e0 = blockIdx.x * C;
    const int e1 = min(e0 + C, E);

    for (int i = tid; i < NB; i += 256) cnt[i] = 0;
    if (tid == 0) carry = 0;
    __syncthreads();

    // phase 1: count bins
    for (int i = e0 + tid; i < e1; i += 256) {
        const int dst = __builtin_nontemporal_load(&ei[E + i]);
        atomicAdd(&cnt[dst >> 6], 1);
    }
    __syncthreads();

    // phase 2: multi-tile exclusive scan; emit tab row; cnt becomes cursor
    for (int base = 0; base < NB; base += 256) {
        const int i = base + tid;
        const int v = (i < NB) ? cnt[i] : 0;
        s[tid] = v;
        __syncthreads();
        for (int d = 1; d < 256; d <<= 1) {
            const int u = (tid >= d) ? s[tid - d] : 0;
            __syncthreads();
            s[tid] += u;
            __syncthreads();
        }
        const int c0 = carry;
        const int excl = c0 + s[tid] - v;
        if (i < NB) {
            tab[(size_t)blockIdx.x * NB + i] = ((unsigned int)excl << 16) | (unsigned int)v;
            cnt[i] = excl;
        }
        __syncthreads();
        if (tid == 0) carry = c0 + s[255];
        __syncthreads();
    }

    // phase 3: place records sorted by bucket
    for (int i = e0 + tid; i < e1; i += 256) {
        const int dst = __builtin_nontemporal_load(&ei[E + i]);
        const int src = __builtin_nontemporal_load(&ei[i]);
        const f32x4 a = __builtin_nontemporal_load((const f32x4*)&ea[(size_t)i * 4]);
        const int p = atomicAdd(&cnt[dst >> 6], 1);
        srec[3 * p + 0] = (unsigned int)src | ((unsigned int)(dst & 63) << 20);
        srec[3 * p + 1] = f2b(a.x) | (f2b(a.y) << 16);
        srec[3 * p + 2] = f2b(a.z) | (f2b(a.w) << 16);
    }
    __syncthreads();

    // phase 4: contiguous coalesced write-out of the sorted chunk
    const int nd = 3 * (e1 - e0);
    unsigned int* qb = queue + (size_t)blockIdx.x * 3 * C;
    for (int d = tid; d < nd; d += 256) qb[d] = srec[d];
}

// =====================  transpose tab[NCHUNK][NB] -> tabT[NB][NCHUNK]  ==============
__global__ __launch_bounds__(256) void transp_kernel(const unsigned int* __restrict__ tab,
                                                     unsigned int* __restrict__ tabT, int NB) {
    __shared__ unsigned int tile[32][33];
    const int tx = threadIdx.x & 31;
    const int ty = threadIdx.x >> 5;  // 0..7
    const int bx = blockIdx.x * 32;   // NB dim
    const int by = blockIdx.y * 32;   // NCHUNK dim
    for (int r = ty; r < 32; r += 8) {
        const int c = bx + tx;
        tile[r][tx] = (c < NB) ? tab[(size_t)(by + r) * NB + c] : 0u;
    }
    __syncthreads();
    for (int r = ty; r < 32; r += 8) {
        const int ob = bx + r;
        if (ob < NB) tabT[(size_t)ob * NCHUNK + by + tx] = tile[tx][r];
    }
}

// =====================  bgather: per-bucket stage + LDS index sort + gather  ========
__global__ __launch_bounds__(256) void bgather_kernel(
    const float* __restrict__ x, const unsigned short* __restrict__ x16,
    const unsigned int* __restrict__ queue, const unsigned int* __restrict__ tabT,
    const float* __restrict__ We, const float* __restrict__ be,
    float* __restrict__ hout, int N, int C) {
    __shared__ unsigned int srec[3 * CAP];   // 18 KB
    __shared__ unsigned short sidx[CAP];     // 3 KB
    __shared__ unsigned int ltab[NCHUNK];    // 2 KB
    __shared__ int soff[NCHUNK];             // 2 KB
    __shared__ int bins[64], boff[64], bcur[64];
    __shared__ int stemp[256];
    __shared__ int scarry;
    const int tid = threadIdx.x;
    const int lane = tid & 63;
    const int w = tid >> 6;
    const int b = blockIdx.x;

    const float w0 = We[lane];
    const float w1 = We[64 + lane];
    const float w2 = We[128 + lane];
    const float w3 = We[192 + lane];
    const float bb = be[lane];

    for (int c = tid; c < NCHUNK; c += 256) ltab[c] = tabT[(size_t)b * NCHUNK + c];
    if (tid < 64) bins[tid] = 0;
    if (tid == 0) scarry = 0;
    __syncthreads();

    // scan run lengths -> staging offsets
    for (int base = 0; base < NCHUNK; base += 256) {
        const int c = base + tid;
        const int v = (int)(ltab[c] & 0xFFFFu);
        stemp[tid] = v;
        __syncthreads();
        for (int d = 1; d < 256; d <<= 1) {
            const int u = (tid >= d) ? stemp[tid - d] : 0;
            __syncthreads();
            stemp[tid] += u;
            __syncthreads();
        }
        const int c0 = scarry;
        soff[c] = c0 + stemp[tid] - v;
        __syncthreads();
        if (tid == 0) scarry = c0 + stemp[255];
        __syncthreads();
    }
    const int cntB = scarry;

    // stage runs into LDS (+ bin count)
    for (int c = tid; c < NCHUNK; c += 256) {
        const unsigned int u = ltab[c];
        const int cntc = (int)(u & 0xFFFFu);
        const unsigned int* qp = queue + (size_t)c * 3 * C + 3 * (size_t)(u >> 16);
        const int sp = soff[c];
        for (int k = 0; k < cntc; ++k) {
            const int p = sp + k;
            if (p >= CAP) break;
            const unsigned int r0 = qp[3 * k + 0];
            srec[3 * p + 0] = r0;
            srec[3 * p + 1] = qp[3 * k + 1];
            srec[3 * p + 2] = qp[3 * k + 2];
            atomicAdd(&bins[(r0 >> 20) & 63], 1);
        }
    }
    __syncthreads();

    // 64-bin exclusive scan (wave 0)
    if (tid < 64) {
        const int mine = bins[tid];
        int incl = mine;
        for (int d = 1; d < 64; d <<= 1) {
            const int up = __shfl_up(incl, d);
            if (tid >= d) incl += up;
        }
        boff[tid] = incl - mine;
        bcur[tid] = incl - mine;
    }
    __syncthreads();

    // place indices
    const int nst = min(cntB, CAP);
    for (int i = tid; i < nst; i += 256) {
        const int dl = (int)((srec[3 * i] >> 20) & 63u);
        const int p = atomicAdd(&bcur[dl], 1);
        sidx[p] = (unsigned short)i;
    }
    __syncthreads();

    // gather: wave w handles nodes d = w + 4*j
    for (int j = 0; j < 16; ++j) {
        const int d = w + 4 * j;
        const int n = b * 64 + d;
        if (n >= N) continue;
        const int s0 = boff[d];
        const int cnt = bins[d];
        float acc = x[(size_t)n * HIDDEN + lane];
        int k = 0;
        for (; k + 4 <= cnt; k += 4) {
            const int i0 = sidx[s0 + k + 0];
            const int i1 = sidx[s0 + k + 1];
            const int i2 = sidx[s0 + k + 2];
            const int i3 = sidx[s0 + k + 3];
            const unsigned int a0 = srec[3 * i0], y0 = srec[3 * i0 + 1], z0 = srec[3 * i0 + 2];
            const unsigned int a1 = srec[3 * i1], y1 = srec[3 * i1 + 1], z1 = srec[3 * i1 + 2];
            const unsigned int a2 = srec[3 * i2], y2 = srec[3 * i2 + 1], z2 = srec[3 * i2 + 2];
            const unsigned int a3 = srec[3 * i3], y3 = srec[3 * i3 + 1], z3 = srec[3 * i3 + 2];
            const float x0 = b2f(x16[(size_t)(a0 & 0xFFFFFu) * HIDDEN + lane]);
            const float x1 = b2f(x16[(size_t)(a1 & 0xFFFFFu) * HIDDEN + lane]);
            const float x2 = b2f(x16[(size_t)(a2 & 0xFFFFFu) * HIDDEN + lane]);
            const float x3 = b2f(x16[(size_t)(a3 & 0xFFFFFu) * HIDDEN + lane]);
            const float p0 = fmaf(bhi(z0), w3, fmaf(blo(z0), w2, fmaf(bhi(y0), w1, fmaf(blo(y0), w0, bb))));
            const float p1 = fmaf(bhi(z1), w3, fmaf(blo(z1), w2, fmaf(bhi(y1), w1, fmaf(blo(y1), w0, bb))));
            const float p2 = fmaf(bhi(z2), w3, fmaf(blo(z2), w2, fmaf(bhi(y2), w1, fmaf(blo(y2), w0, bb))));
            const float p3 = fmaf(bhi(z3), w3, fmaf(blo(z3), w2, fmaf(bhi(y3), w1, fmaf(blo(y3), w0, bb))));
            acc += fmaxf(x0 + p0, 0.0f);
            acc += fmaxf(x1 + p1, 0.0f);
            acc += fmaxf(x2 + p2, 0.0f);
            acc += fmaxf(x3 + p3, 0.0f);
        }
        for (; k < cnt; ++k) {
            const int i0 = sidx[s0 + k];
            const unsigned int a0 = srec[3 * i0], y0 = srec[3 * i0 + 1], z0 = srec[3 * i0 + 2];
            const float xv = b2f(x16[(size_t)(a0 & 0xFFFFFu) * HIDDEN + lane]);
            const float p = fmaf(bhi(z0), w3, fmaf(blo(z0), w2, fmaf(bhi(y0), w1, fmaf(blo(y0), w0, bb))));
            acc += fmaxf(xv + p, 0.0f);
        }
        // overflow (cntB > CAP): astronomically rare, correct-slow path
        if (cntB > CAP) {
            for (int c = 0; c < NCHUNK; ++c) {
                const unsigned int u = ltab[c];
                const int cntc = (int)(u & 0xFFFFu);
                const int sp = soff[c];
                int kst = CAP - sp;
                if (kst < 0) kst = 0;
                if (kst >= cntc) continue;
                const unsigned int* qp = queue + (size_t)c * 3 * C + 3 * (size_t)(u >> 16);
                for (int kk = kst; kk < cntc; ++kk) {
                    const unsigned int a0 = qp[3 * kk];
                    if ((int)((a0 >> 20) & 63u) != d) continue;
                    const unsigned int y0 = qp[3 * kk + 1], z0 = qp[3 * kk + 2];
                    const float xv = b2f(x16[(size_t)(a0 & 0xFFFFFu) * HIDDEN + lane]);
                    const float p = fmaf(bhi(z0), w3, fmaf(blo(z0), w2, fmaf(bhi(y0), w1, fmaf(blo(y0), w0, bb))));
                    acc += fmaxf(xv + p, 0.0f);
                }
            }
        }
        hout[(size_t)n * HIDDEN + lane] = acc;
    }
}

// =====================  MLP via MFMA (LDS-staged W, grid-stride; verified)  =========
__global__ __launch_bounds__(256) void mlp_mfma_kernel(float* __restrict__ hio,
                                                       const float* __restrict__ W1,
                                                       const float* __restrict__ b1,
                                                       const float* __restrict__ W2,
                                                       const float* __restrict__ b2, int N) {
    __shared__ unsigned short w1s[4096], w2s[4096];
    __shared__ unsigned short tlds[4][16 * 72];
    const int tid = threadIdx.x;
    const int lane = tid & 63;
    const int wid = tid >> 6;
    const int g = lane >> 4;
    const int c = lane & 15;

    for (int i = tid; i < 4096; i += 256) {
        w1s[i] = (unsigned short)f2b(W1[i]);
        w2s[i] = (unsigned short)f2b(W2[i]);
    }
    __syncthreads();

    U8 a1[4][2], a2[4][2];
#pragma unroll
    for (int ct = 0; ct < 4; ++ct)
#pragma unroll
        for (int kk = 0; kk < 2; ++kk)
#pragma unroll
            for (int j = 0; j < 8; ++j) {
                a1[ct][kk].s[j] = w1s[(kk * 32 + g * 8 + j) * 64 + ct * 16 + c];
                a2[ct][kk].s[j] = w2s[(kk * 32 + g * 8 + j) * 64 + ct * 16 + c];
            }
    float b1c[4][4], b2c[4][4];
#pragma unroll
    for (int ct = 0; ct < 4; ++ct)
#pragma unroll
        for (int r = 0; r < 4; ++r) {
            b1c[ct][r] = b1[ct * 16 + g * 4 + r];
            b2c[ct][r] = b2[ct * 16 + g * 4 + r];
        }

    unsigned char* myb = (unsigned char*)&tlds[wid][0];
    const int ntiles = (N + 15) >> 4;

    for (int tile = blockIdx.x * 4 + wid; tile < ntiles; tile += gridDim.x * 4) {
        const int row = tile * 16 + c;
        const int rowc = min(row, N - 1);

        U8 b1f[2];
#pragma unroll
        for (int kk = 0; kk < 2; ++kk) {
            const float4* hp = (const float4*)&hio[(size_t)rowc * 64 + kk * 32 + g * 8];
            const float4 lo = hp[0];
            const float4 hi = hp[1];
            b1f[kk].d[0] = f2b(lo.x) | (f2b(lo.y) << 16);
            b1f[kk].d[1] = f2b(lo.z) | (f2b(lo.w) << 16);
            b1f[kk].d[2] = f2b(hi.x) | (f2b(hi.y) << 16);
            b1f[kk].d[3] = f2b(hi.z) | (f2b(hi.w) << 16);
        }
        f32x4 acc1[4];
#pragma unroll
        for (int ct = 0; ct < 4; ++ct) {
            acc1[ct] = (f32x4)(0.0f);
#pragma unroll
            for (int kk = 0; kk < 2; ++kk)
                acc1[ct] = __builtin_amdgcn_mfma_f32_16x16x32_bf16(a1[ct][kk].v, b1f[kk].v,
                                                                   acc1[ct], 0, 0, 0);
        }
#pragma unroll
        for (int ct = 0; ct < 4; ++ct)
#pragma unroll
            for (int rp = 0; rp < 2; ++rp) {
                const float v0 = fmaxf(acc1[ct][2 * rp + 0] + b1c[ct][2 * rp + 0], 0.0f);
                const float v1 = fmaxf(acc1[ct][2 * rp + 1] + b1c[ct][2 * rp + 1], 0.0f);
                *(unsigned int*)(myb + c * 144 + ct * 32 + g * 8 + rp * 4) =
                    f2b(v0) | (f2b(v1) << 16);
            }
        U8 b2f_[2];
#pragma unroll
        for (int kk2 = 0; kk2 < 2; ++kk2) {
            const unsigned int* q = (const unsigned int*)(myb + c * 144 + kk2 * 64 + g * 16);
            b2f_[kk2].d[0] = q[0];
            b2f_[kk2].d[1] = q[1];
            b2f_[kk2].d[2] = q[2];
            b2f_[kk2].d[3] = q[3];
        }
        f32x4 acc2[4];
#pragma unroll
        for (int ct = 0; ct < 4; ++ct) {
            acc2[ct] = (f32x4)(0.0f);
#pragma unroll
            for (int kk2 = 0; kk2 < 2; ++kk2)
                acc2[ct] = __builtin_amdgcn_mfma_f32_16x16x32_bf16(a2[ct][kk2].v, b2f_[kk2].v,
                                                                   acc2[ct], 0, 0, 0);
        }
        if (row < N) {
#pragma unroll
            for (int ct = 0; ct < 4; ++ct)
#pragma unroll
                for (int r = 0; r < 4; ++r)
                    hio[(size_t)row * 64 + ct * 16 + g * 4 + r] = acc2[ct][r] + b2c[ct][r];
        }
    }
}

// =====================  fallback path (ws too small / params out of range)  =========
__global__ __launch_bounds__(256) void mlp_kernel(const float* __restrict__ hin,
                                                  const float* __restrict__ W1,
                                                  const float* __restrict__ b1,
                                                  const float* __restrict__ W2,
                                                  const float* __restrict__ b2,
                                                  float* __restrict__ out, int N) {
    const int lane = threadIdx.x & 63;
    float w1c[64], w2c[64];
#pragma unroll
    for (int k = 0; k < 64; ++k) w1c[k] = W1[k * 64 + lane];
#pragma unroll
    for (int k = 0; k < 64; ++k) w2c[k] = W2[k * 64 + lane];
    const float bb1 = b1[lane];
    const float bb2 = b2[lane];
    int wave = (blockIdx.x * blockDim.x + threadIdx.x) >> 6;
    const int nw = (gridDim.x * blockDim.x) >> 6;
    for (int n = wave; n < N; n += nw) {
        const float h = hin[(size_t)n * HIDDEN + lane];
        float t0 = bb1, t1 = 0.0f;
#pragma unroll
        for (int k = 0; k < 64; k += 2) {
            t0 = fmaf(lane_bcast(h, k), w1c[k], t0);
            t1 = fmaf(lane_bcast(h, k + 1), w1c[k + 1], t1);
        }
        const float t = fmaxf(t0 + t1, 0.0f);
        float o0 = bb2, o1 = 0.0f;
#pragma unroll
        for (int k = 0; k < 64; k += 2) {
            o0 = fmaf(lane_bcast(t, k), w2c[k], o0);
            o1 = fmaf(lane_bcast(t, k + 1), w2c[k + 1], o1);
        }
        out[(size_t)n * HIDDEN + lane] = o0 + o1;
    }
}

__global__ __launch_bounds__(256) void gine_copy_kernel(const float4* __restrict__ x,
                                                        float4* __restrict__ out, int n4) {
    int i = blockIdx.x * blockDim.x + threadIdx.x;
    int stride = gridDim.x * blockDim.x;
    for (; i < n4; i += stride) out[i] = x[i];
}

__global__ __launch_bounds__(256) void gine_edge_kernel(const float* __restrict__ x,
                                                        const int* __restrict__ ei,
                                                        const float4* __restrict__ ea,
                                                        const float* __restrict__ We,
                                                        const float* __restrict__ be,
                                                        float* __restrict__ out, int E) {
    const int lane = threadIdx.x & 63;
    const float w0 = We[lane];
    const float w1 = We[64 + lane];
    const float w2 = We[128 + lane];
    const float w3 = We[192 + lane];
    const float bb = be[lane];
    int wave = (blockIdx.x * blockDim.x + threadIdx.x) >> 6;
    const int nw = (gridDim.x * blockDim.x) >> 6;
    for (int e = wave; e < E; e += nw) {
        const int src = ei[e];
        const int dst = ei[E + e];
        const float4 a = ea[e];
        float m = x[src * HIDDEN + lane] + (bb + a.x * w0 + a.y * w1 + a.z * w2 + a.w * w3);
        m = fmaxf(m, 0.0f);
        atomicAdd(out + dst * HIDDEN + lane, m);
    }
}

extern "C" void kernel_launch(void* const* d_in, const int* in_sizes, int n_in,
                              void* d_out, int out_size, void* d_ws, size_t ws_size,
                              hipStream_t stream) {
    const float* x  = (const float*)d_in[0];
    const int*   ei = (const int*)d_in[1];
    const float* ea = (const float*)d_in[2];
    const float* We = (const float*)d_in[3];
    const float* be = (const float*)d_in[4];
    const float* W1 = (const float*)d_in[5];
    const float* b1 = (const float*)d_in[6];
    const float* W2 = (const float*)d_in[7];
    const float* b2 = (const float*)d_in[8];
    float* out = (float*)d_out;

    const int N = in_sizes[0] / HIDDEN;  // 100000
    const int E = in_sizes[1] / 2;       // 1600000
    const int C = (E + NCHUNK - 1) / NCHUNK;  // 3125
    const int NB = (N + 63) >> 6;             // 1563

    // Workspace layout
    size_t p = 0;
    const size_t x16_ofs  = p; p += ((size_t)N * HIDDEN * 2 + 255) & ~(size_t)255;
    const size_t q_ofs    = p; p += ((size_t)NCHUNK * 3 * C * 4 + 255) & ~(size_t)255;
    const size_t tab_ofs  = p; p += ((size_t)NCHUNK * NB * 4 + 255) & ~(size_t)255;
    const size_t tabT_ofs = p; p += ((size_t)NB * NCHUNK * 4 + 255) & ~(size_t)255;
    const size_t need = p;

    const bool ok = (ws_size >= need) && (NB <= NBMAX) && (C <= CMAX) && (N <= (1 << 20));
    if (!ok) {
        gine_copy_kernel<<<2048, 256, 0, stream>>>((const float4*)x, (float4*)out,
                                                   N * (HIDDEN / 4));
        gine_edge_kernel<<<2048, 256, 0, stream>>>(x, ei, (const float4*)ea, We, be, out, E);
        mlp_kernel<<<2048, 256, 0, stream>>>(out, W1, b1, W2, b2, out, N);
        return;
    }

    char* ws = (char*)d_ws;
    unsigned short* x16   = (unsigned short*)(ws + x16_ofs);
    unsigned int*   queue = (unsigned int*)(ws + q_ofs);
    unsigned int*   tab   = (unsigned int*)(ws + tab_ofs);
    unsigned int*   tabT  = (unsigned int*)(ws + tabT_ofs);

    qsort_kernel<<<NCHUNK, 256, 0, stream>>>((const float4*)x, (ushort4*)x16,
                                             N * (HIDDEN / 4), ei, ea, queue, tab, E, C, NB);
    dim3 tgrid((NB + 31) / 32, NCHUNK / 32);
    transp_kernel<<<tgrid, 256, 0, stream>>>(tab, tabT, NB);
    bgather_kernel<<<NB, 256, 0, stream>>>(x, x16, queue, tabT, We, be, out, N, C);
    mlp_mfma_kernel<<<640, 256, 0, stream>>>(out, W1, b1, W2, b2, N);
}

// Round 15
// 144.427 us; speedup vs baseline: 2.1516x; 1.1989x over previous
//
#include <hip/hip_runtime.h>

#define HIDDEN 64
#define NCHUNK 512
#define CMAX 3200      // max edges per chunk supported by qsort LDS
#define NBMAX 1568     // max buckets supported by qsort LDS
#define CAP 1536       // bgather staging capacity (Poisson mean 1024, +16 sigma)

typedef float f32x4 __attribute__((ext_vector_type(4)));
typedef short bf16x8 __attribute__((ext_vector_type(8)));

union U8 {
    bf16x8 v;
    unsigned short s[8];
    unsigned int d[4];
};

__device__ __forceinline__ float lane_bcast(float v, int l) {
    return __uint_as_float(__builtin_amdgcn_readlane(__float_as_uint(v), l));
}
__device__ __forceinline__ unsigned int f2b(float f) {
    unsigned int u = __float_as_uint(f);
    return (u + 0x7FFFu + ((u >> 16) & 1u)) >> 16;
}
__device__ __forceinline__ float b2f(unsigned int v) { return __uint_as_float(v << 16); }
__device__ __forceinline__ float blo(unsigned int v) { return __uint_as_float(v << 16); }
__device__ __forceinline__ float bhi(unsigned int v) { return __uint_as_float(v & 0xFFFF0000u); }

// =====================  qsort: chunk-local bucket sort, all writes coalesced  =======
__global__ __launch_bounds__(256) void qsort_kernel(const float4* __restrict__ x,
                                                    ushort4* __restrict__ x16, int n4,
                                                    const int* __restrict__ ei,
                                                    const float* __restrict__ ea,
                                                    unsigned int* __restrict__ queue,
                                                    unsigned int* __restrict__ tab,
                                                    int E, int C, int NB) {
    __shared__ unsigned int srec[3 * CMAX];  // 38.4 KB
    __shared__ int cnt[NBMAX];               // 6.3 KB
    __shared__ int s[256];
    __shared__ int carry;
    const int tid = threadIdx.x;

    // fused xcvt
    for (int i = blockIdx.x * blockDim.x + tid; i < n4; i += gridDim.x * blockDim.x) {
        const float4 v = x[i];
        ushort4 o;
        o.x = (unsigned short)f2b(v.x);
        o.y = (unsigned short)f2b(v.y);
        o.z = (unsigned short)f2b(v.z);
        o.w = (unsigned short)f2b(v.w);
        x16[i] = o;
    }

    const int e0 = blockIdx.x * C;
    const int e1 = min(e0 + C, E);

    for (int i = tid; i < NB; i += 256) cnt[i] = 0;
    if (tid == 0) carry = 0;
    __syncthreads();

    for (int i = e0 + tid; i < e1; i += 256) {
        const int dst = __builtin_nontemporal_load(&ei[E + i]);
        atomicAdd(&cnt[dst >> 6], 1);
    }
    __syncthreads();

    for (int base = 0; base < NB; base += 256) {
        const int i = base + tid;
        const int v = (i < NB) ? cnt[i] : 0;
        s[tid] = v;
        __syncthreads();
        for (int d = 1; d < 256; d <<= 1) {
            const int u = (tid >= d) ? s[tid - d] : 0;
            __syncthreads();
            s[tid] += u;
            __syncthreads();
        }
        const int c0 = carry;
        const int excl = c0 + s[tid] - v;
        if (i < NB) {
            tab[(size_t)blockIdx.x * NB + i] = ((unsigned int)excl << 16) | (unsigned int)v;
            cnt[i] = excl;
        }
        __syncthreads();
        if (tid == 0) carry = c0 + s[255];
        __syncthreads();
    }

    for (int i = e0 + tid; i < e1; i += 256) {
        const int dst = __builtin_nontemporal_load(&ei[E + i]);
        const int src = __builtin_nontemporal_load(&ei[i]);
        const f32x4 a = __builtin_nontemporal_load((const f32x4*)&ea[(size_t)i * 4]);
        const int p = atomicAdd(&cnt[dst >> 6], 1);
        srec[3 * p + 0] = (unsigned int)src | ((unsigned int)(dst & 63) << 20);
        srec[3 * p + 1] = f2b(a.x) | (f2b(a.y) << 16);
        srec[3 * p + 2] = f2b(a.z) | (f2b(a.w) << 16);
    }
    __syncthreads();

    const int nd = 3 * (e1 - e0);
    unsigned int* qb = queue + (size_t)blockIdx.x * 3 * C;
    for (int d = tid; d < nd; d += 256) qb[d] = srec[d];
}

// =====================  transpose tab[NCHUNK][NB] -> tabT[NB][NCHUNK]  ==============
__global__ __launch_bounds__(256) void transp_kernel(const unsigned int* __restrict__ tab,
                                                     unsigned int* __restrict__ tabT, int NB) {
    __shared__ unsigned int tile[32][33];
    const int tx = threadIdx.x & 31;
    const int ty = threadIdx.x >> 5;  // 0..7
    const int bx = blockIdx.x * 32;   // NB dim
    const int by = blockIdx.y * 32;   // NCHUNK dim
    for (int r = ty; r < 32; r += 8) {
        const int c = bx + tx;
        tile[r][tx] = (c < NB) ? tab[(size_t)(by + r) * NB + c] : 0u;
    }
    __syncthreads();
    for (int r = ty; r < 32; r += 8) {
        const int ob = bx + r;
        if (ob < NB) tabT[(size_t)ob * NCHUNK + by + tx] = tile[tx][r];
    }
}

// =====================  bgather (512 threads): stage + index sort + gather  ========
__global__ __launch_bounds__(512) void bgather_kernel(
    const float* __restrict__ x, const unsigned short* __restrict__ x16,
    const unsigned int* __restrict__ queue, const unsigned int* __restrict__ tabT,
    const float* __restrict__ We, const float* __restrict__ be,
    float* __restrict__ hout, int N, int C) {
    __shared__ unsigned int srec[3 * CAP];   // 18 KB
    __shared__ unsigned short sidx[CAP];     // 3 KB
    __shared__ unsigned int ltab[NCHUNK];    // 2 KB
    __shared__ int soff[NCHUNK];             // 2 KB
    __shared__ int s[512];                   // 2 KB
    __shared__ int bins[64], boff[64], bcur[64];
    const int tid = threadIdx.x;
    const int lane = tid & 63;
    const int w = tid >> 6;  // 0..7
    const int b = blockIdx.x;

    const float w0 = We[lane];
    const float w1 = We[64 + lane];
    const float w2 = We[128 + lane];
    const float w3 = We[192 + lane];
    const float bb = be[lane];

    // one thread per chunk: load run descriptor
    const unsigned int u = tabT[(size_t)b * NCHUNK + tid];
    ltab[tid] = u;
    if (tid < 64) bins[tid] = 0;

    // single-tile 512-wide scan of run lengths -> staging offsets
    const int v = (int)(u & 0xFFFFu);
    s[tid] = v;
    __syncthreads();
    for (int d = 1; d < 512; d <<= 1) {
        const int up = (tid >= d) ? s[tid - d] : 0;
        __syncthreads();
        s[tid] += up;
        __syncthreads();
    }
    const int sp = s[tid] - v;
    soff[tid] = sp;
    const int cntB = s[511];
    __syncthreads();

    // stage: exactly one run per thread (all 512 in flight)
    {
        const int cntc = v;
        const unsigned int* qp = queue + (size_t)tid * 3 * C + 3 * (size_t)(u >> 16);
        for (int k = 0; k < cntc; ++k) {
            const int p = sp + k;
            if (p >= CAP) break;
            const unsigned int r0 = qp[3 * k + 0];
            srec[3 * p + 0] = r0;
            srec[3 * p + 1] = qp[3 * k + 1];
            srec[3 * p + 2] = qp[3 * k + 2];
            atomicAdd(&bins[(r0 >> 20) & 63], 1);
        }
    }
    __syncthreads();

    // 64-bin exclusive scan (wave 0)
    if (tid < 64) {
        const int mine = bins[tid];
        int incl = mine;
        for (int d = 1; d < 64; d <<= 1) {
            const int up = __shfl_up(incl, d);
            if (tid >= d) incl += up;
        }
        boff[tid] = incl - mine;
        bcur[tid] = incl - mine;
    }
    __syncthreads();

    // place indices
    const int nst = min(cntB, CAP);
    for (int i = tid; i < nst; i += 512) {
        const int dl = (int)((srec[3 * i] >> 20) & 63u);
        const int p = atomicAdd(&bcur[dl], 1);
        sidx[p] = (unsigned short)i;
    }
    __syncthreads();

    // gather: wave w handles nodes d = w + 8*j
    for (int j = 0; j < 8; ++j) {
        const int d = w + 8 * j;
        const int n = b * 64 + d;
        if (n >= N) continue;
        const int s0 = boff[d];
        const int cnt = bins[d];
        float acc = x[(size_t)n * HIDDEN + lane];
        int k = 0;
        for (; k + 4 <= cnt; k += 4) {
            const int i0 = sidx[s0 + k + 0];
            const int i1 = sidx[s0 + k + 1];
            const int i2 = sidx[s0 + k + 2];
            const int i3 = sidx[s0 + k + 3];
            const unsigned int a0 = srec[3 * i0], y0 = srec[3 * i0 + 1], z0 = srec[3 * i0 + 2];
            const unsigned int a1 = srec[3 * i1], y1 = srec[3 * i1 + 1], z1 = srec[3 * i1 + 2];
            const unsigned int a2 = srec[3 * i2], y2 = srec[3 * i2 + 1], z2 = srec[3 * i2 + 2];
            const unsigned int a3 = srec[3 * i3], y3 = srec[3 * i3 + 1], z3 = srec[3 * i3 + 2];
            const float x0 = b2f(x16[(size_t)(a0 & 0xFFFFFu) * HIDDEN + lane]);
            const float x1 = b2f(x16[(size_t)(a1 & 0xFFFFFu) * HIDDEN + lane]);
            const float x2 = b2f(x16[(size_t)(a2 & 0xFFFFFu) * HIDDEN + lane]);
            const float x3 = b2f(x16[(size_t)(a3 & 0xFFFFFu) * HIDDEN + lane]);
            const float p0 = fmaf(bhi(z0), w3, fmaf(blo(z0), w2, fmaf(bhi(y0), w1, fmaf(blo(y0), w0, bb))));
            const float p1 = fmaf(bhi(z1), w3, fmaf(blo(z1), w2, fmaf(bhi(y1), w1, fmaf(blo(y1), w0, bb))));
            const float p2 = fmaf(bhi(z2), w3, fmaf(blo(z2), w2, fmaf(bhi(y2), w1, fmaf(blo(y2), w0, bb))));
            const float p3 = fmaf(bhi(z3), w3, fmaf(blo(z3), w2, fmaf(bhi(y3), w1, fmaf(blo(y3), w0, bb))));
            acc += fmaxf(x0 + p0, 0.0f);
            acc += fmaxf(x1 + p1, 0.0f);
            acc += fmaxf(x2 + p2, 0.0f);
            acc += fmaxf(x3 + p3, 0.0f);
        }
        for (; k < cnt; ++k) {
            const int i0 = sidx[s0 + k];
            const unsigned int a0 = srec[3 * i0], y0 = srec[3 * i0 + 1], z0 = srec[3 * i0 + 2];
            const float xv = b2f(x16[(size_t)(a0 & 0xFFFFFu) * HIDDEN + lane]);
            const float p = fmaf(bhi(z0), w3, fmaf(blo(z0), w2, fmaf(bhi(y0), w1, fmaf(blo(y0), w0, bb))));
            acc += fmaxf(xv + p, 0.0f);
        }
        // overflow (cntB > CAP): astronomically rare, correct-slow path
        if (cntB > CAP) {
            for (int c = 0; c < NCHUNK; ++c) {
                const unsigned int uu = ltab[c];
                const int cntc = (int)(uu & 0xFFFFu);
                const int spc = soff[c];
                int kst = CAP - spc;
                if (kst < 0) kst = 0;
                if (kst >= cntc) continue;
                const unsigned int* qp = queue + (size_t)c * 3 * C + 3 * (size_t)(uu >> 16);
                for (int kk = kst; kk < cntc; ++kk) {
                    const unsigned int a0 = qp[3 * kk];
                    if ((int)((a0 >> 20) & 63u) != d) continue;
                    const unsigned int y0 = qp[3 * kk + 1], z0 = qp[3 * kk + 2];
                    const float xv = b2f(x16[(size_t)(a0 & 0xFFFFFu) * HIDDEN + lane]);
                    const float p = fmaf(bhi(z0), w3, fmaf(blo(z0), w2, fmaf(bhi(y0), w1, fmaf(blo(y0), w0, bb))));
                    acc += fmaxf(xv + p, 0.0f);
                }
            }
        }
        hout[(size_t)n * HIDDEN + lane] = acc;
    }
}

// =====================  MLP via MFMA (LDS-staged W, grid-stride; verified)  =========
__global__ __launch_bounds__(256) void mlp_mfma_kernel(float* __restrict__ hio,
                                                       const float* __restrict__ W1,
                                                       const float* __restrict__ b1,
                                                       const float* __restrict__ W2,
                                                       const float* __restrict__ b2, int N) {
    __shared__ unsigned short w1s[4096], w2s[4096];
    __shared__ unsigned short tlds[4][16 * 72];
    const int tid = threadIdx.x;
    const int lane = tid & 63;
    const int wid = tid >> 6;
    const int g = lane >> 4;
    const int c = lane & 15;

    for (int i = tid; i < 4096; i += 256) {
        w1s[i] = (unsigned short)f2b(W1[i]);
        w2s[i] = (unsigned short)f2b(W2[i]);
    }
    __syncthreads();

    U8 a1[4][2], a2[4][2];
#pragma unroll
    for (int ct = 0; ct < 4; ++ct)
#pragma unroll
        for (int kk = 0; kk < 2; ++kk)
#pragma unroll
            for (int j = 0; j < 8; ++j) {
                a1[ct][kk].s[j] = w1s[(kk * 32 + g * 8 + j) * 64 + ct * 16 + c];
                a2[ct][kk].s[j] = w2s[(kk * 32 + g * 8 + j) * 64 + ct * 16 + c];
            }
    float b1c[4][4], b2c[4][4];
#pragma unroll
    for (int ct = 0; ct < 4; ++ct)
#pragma unroll
        for (int r = 0; r < 4; ++r) {
            b1c[ct][r] = b1[ct * 16 + g * 4 + r];
            b2c[ct][r] = b2[ct * 16 + g * 4 + r];
        }

    unsigned char* myb = (unsigned char*)&tlds[wid][0];
    const int ntiles = (N + 15) >> 4;

    for (int tile = blockIdx.x * 4 + wid; tile < ntiles; tile += gridDim.x * 4) {
        const int row = tile * 16 + c;
        const int rowc = min(row, N - 1);

        U8 b1f[2];
#pragma unroll
        for (int kk = 0; kk < 2; ++kk) {
            const float4* hp = (const float4*)&hio[(size_t)rowc * 64 + kk * 32 + g * 8];
            const float4 lo = hp[0];
            const float4 hi = hp[1];
            b1f[kk].d[0] = f2b(lo.x) | (f2b(lo.y) << 16);
            b1f[kk].d[1] = f2b(lo.z) | (f2b(lo.w) << 16);
            b1f[kk].d[2] = f2b(hi.x) | (f2b(hi.y) << 16);
            b1f[kk].d[3] = f2b(hi.z) | (f2b(hi.w) << 16);
        }
        f32x4 acc1[4];
#pragma unroll
        for (int ct = 0; ct < 4; ++ct) {
            acc1[ct] = (f32x4)(0.0f);
#pragma unroll
            for (int kk = 0; kk < 2; ++kk)
                acc1[ct] = __builtin_amdgcn_mfma_f32_16x16x32_bf16(a1[ct][kk].v, b1f[kk].v,
                                                                   acc1[ct], 0, 0, 0);
        }
#pragma unroll
        for (int ct = 0; ct < 4; ++ct)
#pragma unroll
            for (int rp = 0; rp < 2; ++rp) {
                const float v0 = fmaxf(acc1[ct][2 * rp + 0] + b1c[ct][2 * rp + 0], 0.0f);
                const float v1 = fmaxf(acc1[ct][2 * rp + 1] + b1c[ct][2 * rp + 1], 0.0f);
                *(unsigned int*)(myb + c * 144 + ct * 32 + g * 8 + rp * 4) =
                    f2b(v0) | (f2b(v1) << 16);
            }
        U8 b2f_[2];
#pragma unroll
        for (int kk2 = 0; kk2 < 2; ++kk2) {
            const unsigned int* q = (const unsigned int*)(myb + c * 144 + kk2 * 64 + g * 16);
            b2f_[kk2].d[0] = q[0];
            b2f_[kk2].d[1] = q[1];
            b2f_[kk2].d[2] = q[2];
            b2f_[kk2].d[3] = q[3];
        }
        f32x4 acc2[4];
#pragma unroll
        for (int ct = 0; ct < 4; ++ct) {
            acc2[ct] = (f32x4)(0.0f);
#pragma unroll
            for (int kk2 = 0; kk2 < 2; ++kk2)
                acc2[ct] = __builtin_amdgcn_mfma_f32_16x16x32_bf16(a2[ct][kk2].v, b2f_[kk2].v,
                                                                   acc2[ct], 0, 0, 0);
        }
        if (row < N) {
#pragma unroll
            for (int ct = 0; ct < 4; ++ct)
#pragma unroll
                for (int r = 0; r < 4; ++r)
                    hio[(size_t)row * 64 + ct * 16 + g * 4 + r] = acc2[ct][r] + b2c[ct][r];
        }
    }
}

// =====================  fallback path (ws too small / params out of range)  =========
__global__ __launch_bounds__(256) void mlp_kernel(const float* __restrict__ hin,
                                                  const float* __restrict__ W1,
                                                  const float* __restrict__ b1,
                                                  const float* __restrict__ W2,
                                                  const float* __restrict__ b2,
                                                  float* __restrict__ out, int N) {
    const int lane = threadIdx.x & 63;
    float w1c[64], w2c[64];
#pragma unroll
    for (int k = 0; k < 64; ++k) w1c[k] = W1[k * 64 + lane];
#pragma unroll
    for (int k = 0; k < 64; ++k) w2c[k] = W2[k * 64 + lane];
    const float bb1 = b1[lane];
    const float bb2 = b2[lane];
    int wave = (blockIdx.x * blockDim.x + threadIdx.x) >> 6;
    const int nw = (gridDim.x * blockDim.x) >> 6;
    for (int n = wave; n < N; n += nw) {
        const float h = hin[(size_t)n * HIDDEN + lane];
        float t0 = bb1, t1 = 0.0f;
#pragma unroll
        for (int k = 0; k < 64; k += 2) {
            t0 = fmaf(lane_bcast(h, k), w1c[k], t0);
            t1 = fmaf(lane_bcast(h, k + 1), w1c[k + 1], t1);
        }
        const float t = fmaxf(t0 + t1, 0.0f);
        float o0 = bb2, o1 = 0.0f;
#pragma unroll
        for (int k = 0; k < 64; k += 2) {
            o0 = fmaf(lane_bcast(t, k), w2c[k], o0);
            o1 = fmaf(lane_bcast(t, k + 1), w2c[k + 1], o1);
        }
        out[(size_t)n * HIDDEN + lane] = o0 + o1;
    }
}

__global__ __launch_bounds__(256) void gine_copy_kernel(const float4* __restrict__ x,
                                                        float4* __restrict__ out, int n4) {
    int i = blockIdx.x * blockDim.x + threadIdx.x;
    int stride = gridDim.x * blockDim.x;
    for (; i < n4; i += stride) out[i] = x[i];
}

__global__ __launch_bounds__(256) void gine_edge_kernel(const float* __restrict__ x,
                                                        const int* __restrict__ ei,
                                                        const float4* __restrict__ ea,
                                                        const float* __restrict__ We,
                                                        const float* __restrict__ be,
                                                        float* __restrict__ out, int E) {
    const int lane = threadIdx.x & 63;
    const float w0 = We[lane];
    const float w1 = We[64 + lane];
    const float w2 = We[128 + lane];
    const float w3 = We[192 + lane];
    const float bb = be[lane];
    int wave = (blockIdx.x * blockDim.x + threadIdx.x) >> 6;
    const int nw = (gridDim.x * blockDim.x) >> 6;
    for (int e = wave; e < E; e += nw) {
        const int src = ei[e];
        const int dst = ei[E + e];
        const float4 a = ea[e];
        float m = x[src * HIDDEN + lane] + (bb + a.x * w0 + a.y * w1 + a.z * w2 + a.w * w3);
        m = fmaxf(m, 0.0f);
        atomicAdd(out + dst * HIDDEN + lane, m);
    }
}

extern "C" void kernel_launch(void* const* d_in, const int* in_sizes, int n_in,
                              void* d_out, int out_size, void* d_ws, size_t ws_size,
                              hipStream_t stream) {
    const float* x  = (const float*)d_in[0];
    const int*   ei = (const int*)d_in[1];
    const float* ea = (const float*)d_in[2];
    const float* We = (const float*)d_in[3];
    const float* be = (const float*)d_in[4];
    const float* W1 = (const float*)d_in[5];
    const float* b1 = (const float*)d_in[6];
    const float* W2 = (const float*)d_in[7];
    const float* b2 = (const float*)d_in[8];
    float* out = (float*)d_out;

    const int N = in_sizes[0] / HIDDEN;  // 100000
    const int E = in_sizes[1] / 2;       // 1600000
    const int C = (E + NCHUNK - 1) / NCHUNK;  // 3125
    const int NB = (N + 63) >> 6;             // 1563

    // Workspace layout
    size_t p = 0;
    const size_t x16_ofs  = p; p += ((size_t)N * HIDDEN * 2 + 255) & ~(size_t)255;
    const size_t q_ofs    = p; p += ((size_t)NCHUNK * 3 * C * 4 + 255) & ~(size_t)255;
    const size_t tab_ofs  = p; p += ((size_t)NCHUNK * NB * 4 + 255) & ~(size_t)255;
    const size_t tabT_ofs = p; p += ((size_t)NB * NCHUNK * 4 + 255) & ~(size_t)255;
    const size_t need = p;

    const bool ok = (ws_size >= need) && (NB <= NBMAX) && (C <= CMAX) && (N <= (1 << 20));
    if (!ok) {
        gine_copy_kernel<<<2048, 256, 0, stream>>>((const float4*)x, (float4*)out,
                                                   N * (HIDDEN / 4));
        gine_edge_kernel<<<2048, 256, 0, stream>>>(x, ei, (const float4*)ea, We, be, out, E);
        mlp_kernel<<<2048, 256, 0, stream>>>(out, W1, b1, W2, b2, out, N);
        return;
    }

    char* ws = (char*)d_ws;
    unsigned short* x16   = (unsigned short*)(ws + x16_ofs);
    unsigned int*   queue = (unsigned int*)(ws + q_ofs);
    unsigned int*   tab   = (unsigned int*)(ws + tab_ofs);
    unsigned int*   tabT  = (unsigned int*)(ws + tabT_ofs);

    qsort_kernel<<<NCHUNK, 256, 0, stream>>>((const float4*)x, (ushort4*)x16,
                                             N * (HIDDEN / 4), ei, ea, queue, tab, E, C, NB);
    dim3 tgrid((NB + 31) / 32, NCHUNK / 32);
    transp_kernel<<<tgrid, 256, 0, stream>>>(tab, tabT, NB);
    bgather_kernel<<<NB, 512, 0, stream>>>(x, x16, queue, tabT, We, be, out, N, C);
    mlp_mfma_kernel<<<640, 256, 0, stream>>>(out, W1, b1, W2, b2, N);
}

// Round 16
// 143.678 us; speedup vs baseline: 2.1628x; 1.0052x over previous
//
#include <hip/hip_runtime.h>

#define HIDDEN 64
#define NCHUNK 512
#define CMAX 3200      // max edges per chunk supported by qsort LDS
#define NBMAX 1568     // max buckets supported by qsort LDS
#define CAP 1536       // bgather staging capacity (Poisson mean 1024, +16 sigma)

typedef float f32x4 __attribute__((ext_vector_type(4)));
typedef short bf16x8 __attribute__((ext_vector_type(8)));
typedef short s16x2 __attribute__((ext_vector_type(2)));

union U8 {
    bf16x8 v;
    unsigned short s[8];
    unsigned int d[4];
};
union U2 {
    s16x2 v;
    unsigned int d;
};

__device__ __forceinline__ float lane_bcast(float v, int l) {
    return __uint_as_float(__builtin_amdgcn_readlane(__float_as_uint(v), l));
}
__device__ __forceinline__ unsigned int f2b(float f) {
    unsigned int u = __float_as_uint(f);
    return (u + 0x7FFFu + ((u >> 16) & 1u)) >> 16;
}
__device__ __forceinline__ float b2f(unsigned int v) { return __uint_as_float(v << 16); }
__device__ __forceinline__ float blo(unsigned int v) { return __uint_as_float(v << 16); }
__device__ __forceinline__ float bhi(unsigned int v) { return __uint_as_float(v & 0xFFFF0000u); }

// 2-way bf16 dot product with f32 accumulate: p = a.lo*b.lo + a.hi*b.hi + c
__device__ __forceinline__ float dot2b(unsigned int a, unsigned int b, float c) {
#if __has_builtin(__builtin_amdgcn_fdot2_f32_bf16)
    U2 ua, ub;
    ua.d = a;
    ub.d = b;
    return __builtin_amdgcn_fdot2_f32_bf16(ua.v, ub.v, c, false);
#else
    return fmaf(bhi(a), bhi(b), fmaf(blo(a), blo(b), c));
#endif
}

// =====================  qsort: chunk-local bucket sort, all writes coalesced  =======
__global__ __launch_bounds__(256) void qsort_kernel(const float4* __restrict__ x,
                                                    ushort4* __restrict__ x16, int n4,
                                                    const int* __restrict__ ei,
                                                    const float* __restrict__ ea,
                                                    unsigned int* __restrict__ queue,
                                                    unsigned int* __restrict__ tab,
                                                    int E, int C, int NB) {
    __shared__ unsigned int srec[3 * CMAX];  // 38.4 KB
    __shared__ int cnt[NBMAX];               // 6.3 KB
    __shared__ int s[256];
    __shared__ int carry;
    const int tid = threadIdx.x;

    // fused xcvt
    for (int i = blockIdx.x * blockDim.x + tid; i < n4; i += gridDim.x * blockDim.x) {
        const float4 v = x[i];
        ushort4 o;
        o.x = (unsigned short)f2b(v.x);
        o.y = (unsigned short)f2b(v.y);
        o.z = (unsigned short)f2b(v.z);
        o.w = (unsigned short)f2b(v.w);
        x16[i] = o;
    }

    const int e0 = blockIdx.x * C;
    const int e1 = min(e0 + C, E);

    for (int i = tid; i < NB; i += 256) cnt[i] = 0;
    if (tid == 0) carry = 0;
    __syncthreads();

    for (int i = e0 + tid; i < e1; i += 256) {
        const int dst = __builtin_nontemporal_load(&ei[E + i]);
        atomicAdd(&cnt[dst >> 6], 1);
    }
    __syncthreads();

    for (int base = 0; base < NB; base += 256) {
        const int i = base + tid;
        const int v = (i < NB) ? cnt[i] : 0;
        s[tid] = v;
        __syncthreads();
        for (int d = 1; d < 256; d <<= 1) {
            const int u = (tid >= d) ? s[tid - d] : 0;
            __syncthreads();
            s[tid] += u;
            __syncthreads();
        }
        const int c0 = carry;
        const int excl = c0 + s[tid] - v;
        if (i < NB) {
            tab[(size_t)blockIdx.x * NB + i] = ((unsigned int)excl << 16) | (unsigned int)v;
            cnt[i] = excl;
        }
        __syncthreads();
        if (tid == 0) carry = c0 + s[255];
        __syncthreads();
    }

    for (int i = e0 + tid; i < e1; i += 256) {
        const int dst = __builtin_nontemporal_load(&ei[E + i]);
        const int src = __builtin_nontemporal_load(&ei[i]);
        const f32x4 a = __builtin_nontemporal_load((const f32x4*)&ea[(size_t)i * 4]);
        const int p = atomicAdd(&cnt[dst >> 6], 1);
        srec[3 * p + 0] = (unsigned int)src | ((unsigned int)(dst & 63) << 20);
        srec[3 * p + 1] = f2b(a.x) | (f2b(a.y) << 16);
        srec[3 * p + 2] = f2b(a.z) | (f2b(a.w) << 16);
    }
    __syncthreads();

    const int nd = 3 * (e1 - e0);
    unsigned int* qb = queue + (size_t)blockIdx.x * 3 * C;
    for (int d = tid; d < nd; d += 256) qb[d] = srec[d];
}

// =====================  transpose tab[NCHUNK][NB] -> tabT[NB][NCHUNK]  ==============
__global__ __launch_bounds__(256) void transp_kernel(const unsigned int* __restrict__ tab,
                                                     unsigned int* __restrict__ tabT, int NB) {
    __shared__ unsigned int tile[32][33];
    const int tx = threadIdx.x & 31;
    const int ty = threadIdx.x >> 5;  // 0..7
    const int bx = blockIdx.x * 32;   // NB dim
    const int by = blockIdx.y * 32;   // NCHUNK dim
    for (int r = ty; r < 32; r += 8) {
        const int c = bx + tx;
        tile[r][tx] = (c < NB) ? tab[(size_t)(by + r) * NB + c] : 0u;
    }
    __syncthreads();
    for (int r = ty; r < 32; r += 8) {
        const int ob = bx + r;
        if (ob < NB) tabT[(size_t)ob * NCHUNK + by + tx] = tile[tx][r];
    }
}

// =====================  bgather (512 threads): stage + index sort + gather  ========
__global__ __launch_bounds__(512) void bgather_kernel(
    const float* __restrict__ x, const unsigned short* __restrict__ x16,
    const unsigned int* __restrict__ queue, const unsigned int* __restrict__ tabT,
    const float* __restrict__ We, const float* __restrict__ be,
    float* __restrict__ hout, int N, int C) {
    __shared__ unsigned int srec[3 * CAP];   // 18 KB
    __shared__ unsigned short sidx[CAP];     // 3 KB (premultiplied by 3)
    __shared__ unsigned int ltab[NCHUNK];    // 2 KB
    __shared__ int soff[NCHUNK];             // 2 KB
    __shared__ int bins[64], boff[64], bcur[64];
    __shared__ int wtot[8], wexc[8];
    __shared__ int totB;
    const int tid = threadIdx.x;
    const int lane = tid & 63;
    const int w = tid >> 6;  // 0..7
    const int b = blockIdx.x;

    // packed bf16 lane weights for dot2
    const unsigned int pw01 = f2b(We[lane]) | (f2b(We[64 + lane]) << 16);
    const unsigned int pw23 = f2b(We[128 + lane]) | (f2b(We[192 + lane]) << 16);
    const float bb = be[lane];

    // one thread per chunk: load run descriptor
    const unsigned int u = tabT[(size_t)b * NCHUNK + tid];
    ltab[tid] = u;
    if (tid < 64) bins[tid] = 0;

    // hierarchical scan of run lengths (wave shfl + 8-way cross-wave)
    const int v = (int)(u & 0xFFFFu);
    int incl = v;
#pragma unroll
    for (int d = 1; d < 64; d <<= 1) {
        const int up = __shfl_up(incl, d);
        if (lane >= d) incl += up;
    }
    if (lane == 63) wtot[w] = incl;
    __syncthreads();
    if (tid < 8) {
        const int mine = wtot[tid];
        int wi = mine;
#pragma unroll
        for (int d = 1; d < 8; d <<= 1) {
            const int up = __shfl_up(wi, d);
            if (tid >= d) wi += up;
        }
        wexc[tid] = wi - mine;
        if (tid == 7) totB = wi;
    }
    __syncthreads();
    const int sp = wexc[w] + incl - v;
    soff[tid] = sp;
    const int cntB = totB;

    // stage: exactly one run per thread (all 512 in flight)
    {
        const unsigned int* qp = queue + (size_t)tid * 3 * C + 3 * (size_t)(u >> 16);
        for (int k = 0; k < v; ++k) {
            const int p = sp + k;
            if (p >= CAP) break;
            const unsigned int r0 = qp[3 * k + 0];
            srec[3 * p + 0] = r0;
            srec[3 * p + 1] = qp[3 * k + 1];
            srec[3 * p + 2] = qp[3 * k + 2];
            atomicAdd(&bins[(r0 >> 20) & 63], 1);
        }
    }
    __syncthreads();

    // 64-bin exclusive scan (wave 0)
    if (tid < 64) {
        const int mine = bins[tid];
        int bi = mine;
#pragma unroll
        for (int d = 1; d < 64; d <<= 1) {
            const int up = __shfl_up(bi, d);
            if (tid >= d) bi += up;
        }
        boff[tid] = bi - mine;
        bcur[tid] = bi - mine;
    }
    __syncthreads();

    // place premultiplied indices
    const int nst = min(cntB, CAP);
    for (int i = tid; i < nst; i += 512) {
        const int dl = (int)((srec[3 * i] >> 20) & 63u);
        const int p = atomicAdd(&bcur[dl], 1);
        sidx[p] = (unsigned short)(3 * i);
    }
    __syncthreads();

    // gather: wave w handles nodes d = w + 8*j
    for (int j = 0; j < 8; ++j) {
        const int d = w + 8 * j;
        const int n = b * 64 + d;
        if (n >= N) continue;
        const int s0 = boff[d];
        const int cnt = bins[d];
        float acc = x[(size_t)n * HIDDEN + lane];
        int k = 0;
        for (; k + 4 <= cnt; k += 4) {
            const int i0 = sidx[s0 + k + 0];
            const int i1 = sidx[s0 + k + 1];
            const int i2 = sidx[s0 + k + 2];
            const int i3 = sidx[s0 + k + 3];
            const unsigned int a0 = srec[i0], y0 = srec[i0 + 1], z0 = srec[i0 + 2];
            const unsigned int a1 = srec[i1], y1 = srec[i1 + 1], z1 = srec[i1 + 2];
            const unsigned int a2 = srec[i2], y2 = srec[i2 + 1], z2 = srec[i2 + 2];
            const unsigned int a3 = srec[i3], y3 = srec[i3 + 1], z3 = srec[i3 + 2];
            const float x0 = b2f(x16[(size_t)(a0 & 0xFFFFFu) * HIDDEN + lane]);
            const float x1 = b2f(x16[(size_t)(a1 & 0xFFFFFu) * HIDDEN + lane]);
            const float x2 = b2f(x16[(size_t)(a2 & 0xFFFFFu) * HIDDEN + lane]);
            const float x3 = b2f(x16[(size_t)(a3 & 0xFFFFFu) * HIDDEN + lane]);
            const float p0 = dot2b(y0, pw01, dot2b(z0, pw23, bb + x0));
            const float p1 = dot2b(y1, pw01, dot2b(z1, pw23, bb + x1));
            const float p2 = dot2b(y2, pw01, dot2b(z2, pw23, bb + x2));
            const float p3 = dot2b(y3, pw01, dot2b(z3, pw23, bb + x3));
            acc += fmaxf(p0, 0.0f);
            acc += fmaxf(p1, 0.0f);
            acc += fmaxf(p2, 0.0f);
            acc += fmaxf(p3, 0.0f);
        }
        for (; k < cnt; ++k) {
            const int i0 = sidx[s0 + k];
            const unsigned int a0 = srec[i0], y0 = srec[i0 + 1], z0 = srec[i0 + 2];
            const float xv = b2f(x16[(size_t)(a0 & 0xFFFFFu) * HIDDEN + lane]);
            acc += fmaxf(dot2b(y0, pw01, dot2b(z0, pw23, bb + xv)), 0.0f);
        }
        // overflow (cntB > CAP): astronomically rare, correct-slow path
        if (cntB > CAP) {
            for (int c = 0; c < NCHUNK; ++c) {
                const unsigned int uu = ltab[c];
                const int cntc = (int)(uu & 0xFFFFu);
                const int spc = soff[c];
                int kst = CAP - spc;
                if (kst < 0) kst = 0;
                if (kst >= cntc) continue;
                const unsigned int* qp = queue + (size_t)c * 3 * C + 3 * (size_t)(uu >> 16);
                for (int kk = kst; kk < cntc; ++kk) {
                    const unsigned int a0 = qp[3 * kk];
                    if ((int)((a0 >> 20) & 63u) != d) continue;
                    const unsigned int y0 = qp[3 * kk + 1], z0 = qp[3 * kk + 2];
                    const float xv = b2f(x16[(size_t)(a0 & 0xFFFFFu) * HIDDEN + lane]);
                    acc += fmaxf(dot2b(y0, pw01, dot2b(z0, pw23, bb + xv)), 0.0f);
                }
            }
        }
        hout[(size_t)n * HIDDEN + lane] = acc;
    }
}

// =====================  MLP via MFMA (LDS-staged W, grid-stride; verified)  =========
__global__ __launch_bounds__(256) void mlp_mfma_kernel(float* __restrict__ hio,
                                                       const float* __restrict__ W1,
                                                       const float* __restrict__ b1,
                                                       const float* __restrict__ W2,
                                                       const float* __restrict__ b2, int N) {
    __shared__ unsigned short w1s[4096], w2s[4096];
    __shared__ unsigned short tlds[4][16 * 72];
    const int tid = threadIdx.x;
    const int lane = tid & 63;
    const int wid = tid >> 6;
    const int g = lane >> 4;
    const int c = lane & 15;

    for (int i = tid; i < 4096; i += 256) {
        w1s[i] = (unsigned short)f2b(W1[i]);
        w2s[i] = (unsigned short)f2b(W2[i]);
    }
    __syncthreads();

    U8 a1[4][2], a2[4][2];
#pragma unroll
    for (int ct = 0; ct < 4; ++ct)
#pragma unroll
        for (int kk = 0; kk < 2; ++kk)
#pragma unroll
            for (int j = 0; j < 8; ++j) {
                a1[ct][kk].s[j] = w1s[(kk * 32 + g * 8 + j) * 64 + ct * 16 + c];
                a2[ct][kk].s[j] = w2s[(kk * 32 + g * 8 + j) * 64 + ct * 16 + c];
            }
    float b1c[4][4], b2c[4][4];
#pragma unroll
    for (int ct = 0; ct < 4; ++ct)
#pragma unroll
        for (int r = 0; r < 4; ++r) {
            b1c[ct][r] = b1[ct * 16 + g * 4 + r];
            b2c[ct][r] = b2[ct * 16 + g * 4 + r];
        }

    unsigned char* myb = (unsigned char*)&tlds[wid][0];
    const int ntiles = (N + 15) >> 4;

    for (int tile = blockIdx.x * 4 + wid; tile < ntiles; tile += gridDim.x * 4) {
        const int row = tile * 16 + c;
        const int rowc = min(row, N - 1);

        U8 b1f[2];
#pragma unroll
        for (int kk = 0; kk < 2; ++kk) {
            const float4* hp = (const float4*)&hio[(size_t)rowc * 64 + kk * 32 + g * 8];
            const float4 lo = hp[0];
            const float4 hi = hp[1];
            b1f[kk].d[0] = f2b(lo.x) | (f2b(lo.y) << 16);
            b1f[kk].d[1] = f2b(lo.z) | (f2b(lo.w) << 16);
            b1f[kk].d[2] = f2b(hi.x) | (f2b(hi.y) << 16);
            b1f[kk].d[3] = f2b(hi.z) | (f2b(hi.w) << 16);
        }
        f32x4 acc1[4];
#pragma unroll
        for (int ct = 0; ct < 4; ++ct) {
            acc1[ct] = (f32x4)(0.0f);
#pragma unroll
            for (int kk = 0; kk < 2; ++kk)
                acc1[ct] = __builtin_amdgcn_mfma_f32_16x16x32_bf16(a1[ct][kk].v, b1f[kk].v,
                                                                   acc1[ct], 0, 0, 0);
        }
#pragma unroll
        for (int ct = 0; ct < 4; ++ct)
#pragma unroll
            for (int rp = 0; rp < 2; ++rp) {
                const float v0 = fmaxf(acc1[ct][2 * rp + 0] + b1c[ct][2 * rp + 0], 0.0f);
                const float v1 = fmaxf(acc1[ct][2 * rp + 1] + b1c[ct][2 * rp + 1], 0.0f);
                *(unsigned int*)(myb + c * 144 + ct * 32 + g * 8 + rp * 4) =
                    f2b(v0) | (f2b(v1) << 16);
            }
        U8 b2f_[2];
#pragma unroll
        for (int kk2 = 0; kk2 < 2; ++kk2) {
            const unsigned int* q = (const unsigned int*)(myb + c * 144 + kk2 * 64 + g * 16);
            b2f_[kk2].d[0] = q[0];
            b2f_[kk2].d[1] = q[1];
            b2f_[kk2].d[2] = q[2];
            b2f_[kk2].d[3] = q[3];
        }
        f32x4 acc2[4];
#pragma unroll
        for (int ct = 0; ct < 4; ++ct) {
            acc2[ct] = (f32x4)(0.0f);
#pragma unroll
            for (int kk2 = 0; kk2 < 2; ++kk2)
                acc2[ct] = __builtin_amdgcn_mfma_f32_16x16x32_bf16(a2[ct][kk2].v, b2f_[kk2].v,
                                                                   acc2[ct], 0, 0, 0);
        }
        if (row < N) {
#pragma unroll
            for (int ct = 0; ct < 4; ++ct)
#pragma unroll
                for (int r = 0; r < 4; ++r)
                    hio[(size_t)row * 64 + ct * 16 + g * 4 + r] = acc2[ct][r] + b2c[ct][r];
        }
    }
}

// =====================  fallback path (ws too small / params out of range)  =========
__global__ __launch_bounds__(256) void mlp_kernel(const float* __restrict__ hin,
                                                  const float* __restrict__ W1,
                                                  const float* __restrict__ b1,
                                                  const float* __restrict__ W2,
                                                  const float* __restrict__ b2,
                                                  float* __restrict__ out, int N) {
    const int lane = threadIdx.x & 63;
    float w1c[64], w2c[64];
#pragma unroll
    for (int k = 0; k < 64; ++k) w1c[k] = W1[k * 64 + lane];
#pragma unroll
    for (int k = 0; k < 64; ++k) w2c[k] = W2[k * 64 + lane];
    const float bb1 = b1[lane];
    const float bb2 = b2[lane];
    int wave = (blockIdx.x * blockDim.x + threadIdx.x) >> 6;
    const int nw = (gridDim.x * blockDim.x) >> 6;
    for (int n = wave; n < N; n += nw) {
        const float h = hin[(size_t)n * HIDDEN + lane];
        float t0 = bb1, t1 = 0.0f;
#pragma unroll
        for (int k = 0; k < 64; k += 2) {
            t0 = fmaf(lane_bcast(h, k), w1c[k], t0);
            t1 = fmaf(lane_bcast(h, k + 1), w1c[k + 1], t1);
        }
        const float t = fmaxf(t0 + t1, 0.0f);
        float o0 = bb2, o1 = 0.0f;
#pragma unroll
        for (int k = 0; k < 64; k += 2) {
            o0 = fmaf(lane_bcast(t, k), w2c[k], o0);
            o1 = fmaf(lane_bcast(t, k + 1), w2c[k + 1], o1);
        }
        out[(size_t)n * HIDDEN + lane] = o0 + o1;
    }
}

__global__ __launch_bounds__(256) void gine_copy_kernel(const float4* __restrict__ x,
                                                        float4* __restrict__ out, int n4) {
    int i = blockIdx.x * blockDim.x + threadIdx.x;
    int stride = gridDim.x * blockDim.x;
    for (; i < n4; i += stride) out[i] = x[i];
}

__global__ __launch_bounds__(256) void gine_edge_kernel(const float* __restrict__ x,
                                                        const int* __restrict__ ei,
                                                        const float4* __restrict__ ea,
                                                        const float* __restrict__ We,
                                                        const float* __restrict__ be,
                                                        float* __restrict__ out, int E) {
    const int lane = threadIdx.x & 63;
    const float w0 = We[lane];
    const float w1 = We[64 + lane];
    const float w2 = We[128 + lane];
    const float w3 = We[192 + lane];
    const float bb = be[lane];
    int wave = (blockIdx.x * blockDim.x + threadIdx.x) >> 6;
    const int nw = (gridDim.x * blockDim.x) >> 6;
    for (int e = wave; e < E; e += nw) {
        const int src = ei[e];
        const int dst = ei[E + e];
        const float4 a = ea[e];
        float m = x[src * HIDDEN + lane] + (bb + a.x * w0 + a.y * w1 + a.z * w2 + a.w * w3);
        m = fmaxf(m, 0.0f);
        atomicAdd(out + dst * HIDDEN + lane, m);
    }
}

extern "C" void kernel_launch(void* const* d_in, const int* in_sizes, int n_in,
                              void* d_out, int out_size, void* d_ws, size_t ws_size,
                              hipStream_t stream) {
    const float* x  = (const float*)d_in[0];
    const int*   ei = (const int*)d_in[1];
    const float* ea = (const float*)d_in[2];
    const float* We = (const float*)d_in[3];
    const float* be = (const float*)d_in[4];
    const float* W1 = (const float*)d_in[5];
    const float* b1 = (const float*)d_in[6];
    const float* W2 = (const float*)d_in[7];
    const float* b2 = (const float*)d_in[8];
    float* out = (float*)d_out;

    const int N = in_sizes[0] / HIDDEN;  // 100000
    const int E = in_sizes[1] / 2;       // 1600000
    const int C = (E + NCHUNK - 1) / NCHUNK;  // 3125
    const int NB = (N + 63) >> 6;             // 1563

    // Workspace layout
    size_t p = 0;
    const size_t x16_ofs  = p; p += ((size_t)N * HIDDEN * 2 + 255) & ~(size_t)255;
    const size_t q_ofs    = p; p += ((size_t)NCHUNK * 3 * C * 4 + 255) & ~(size_t)255;
    const size_t tab_ofs  = p; p += ((size_t)NCHUNK * NB * 4 + 255) & ~(size_t)255;
    const size_t tabT_ofs = p; p += ((size_t)NB * NCHUNK * 4 + 255) & ~(size_t)255;
    const size_t need = p;

    const bool ok = (ws_size >= need) && (NB <= NBMAX) && (C <= CMAX) && (N <= (1 << 20));
    if (!ok) {
        gine_copy_kernel<<<2048, 256, 0, stream>>>((const float4*)x, (float4*)out,
                                                   N * (HIDDEN / 4));
        gine_edge_kernel<<<2048, 256, 0, stream>>>(x, ei, (const float4*)ea, We, be, out, E);
        mlp_kernel<<<2048, 256, 0, stream>>>(out, W1, b1, W2, b2, out, N);
        return;
    }

    char* ws = (char*)d_ws;
    unsigned short* x16   = (unsigned short*)(ws + x16_ofs);
    unsigned int*   queue = (unsigned int*)(ws + q_ofs);
    unsigned int*   tab   = (unsigned int*)(ws + tab_ofs);
    unsigned int*   tabT  = (unsigned int*)(ws + tabT_ofs);

    qsort_kernel<<<NCHUNK, 256, 0, stream>>>((const float4*)x, (ushort4*)x16,
                                             N * (HIDDEN / 4), ei, ea, queue, tab, E, C, NB);
    dim3 tgrid((NB + 31) / 32, NCHUNK / 32);
    transp_kernel<<<tgrid, 256, 0, stream>>>(tab, tabT, NB);
    bgather_kernel<<<NB, 512, 0, stream>>>(x, x16, queue, tabT, We, be, out, N, C);
    mlp_mfma_kernel<<<640, 256, 0, stream>>>(out, W1, b1, W2, b2, N);
}

// Round 17
// 132.939 us; speedup vs baseline: 2.3375x; 1.0808x over previous
//
#include <hip/hip_runtime.h>

#define HIDDEN 64
#define NCHUNK 512
#define CMAX 3200      // max edges per chunk supported by qsort LDS
#define NBMAX 1568     // max buckets supported by qsort LDS
#define CAP 1536       // bgather staging capacity (Poisson mean 1024, +16 sigma)

typedef float f32x4 __attribute__((ext_vector_type(4)));
typedef short bf16x8 __attribute__((ext_vector_type(8)));
typedef short s16x2 __attribute__((ext_vector_type(2)));

union U8 {
    bf16x8 v;
    unsigned short s[8];
    unsigned int d[4];
};
union U2 {
    s16x2 v;
    unsigned int d;
};

__device__ __forceinline__ float lane_bcast(float v, int l) {
    return __uint_as_float(__builtin_amdgcn_readlane(__float_as_uint(v), l));
}
__device__ __forceinline__ unsigned int f2b(float f) {
    unsigned int u = __float_as_uint(f);
    return (u + 0x7FFFu + ((u >> 16) & 1u)) >> 16;
}
__device__ __forceinline__ float b2f(unsigned int v) { return __uint_as_float(v << 16); }
__device__ __forceinline__ float blo(unsigned int v) { return __uint_as_float(v << 16); }
__device__ __forceinline__ float bhi(unsigned int v) { return __uint_as_float(v & 0xFFFF0000u); }

// 2-way bf16 dot product with f32 accumulate
__device__ __forceinline__ float dot2b(unsigned int a, unsigned int b, float c) {
#if __has_builtin(__builtin_amdgcn_fdot2_f32_bf16)
    U2 ua, ub;
    ua.d = a;
    ub.d = b;
    return __builtin_amdgcn_fdot2_f32_bf16(ua.v, ub.v, c, false);
#else
    return fmaf(bhi(a), bhi(b), fmaf(blo(a), blo(b), c));
#endif
}

// =====================  qsort: chunk-local bucket sort, all writes coalesced  =======
__global__ __launch_bounds__(256) void qsort_kernel(const float4* __restrict__ x,
                                                    ushort4* __restrict__ x16, int n4,
                                                    const int* __restrict__ ei,
                                                    const float* __restrict__ ea,
                                                    unsigned int* __restrict__ queue,
                                                    unsigned int* __restrict__ tab,
                                                    int E, int C, int NB) {
    __shared__ unsigned int srec[3 * CMAX];  // 38.4 KB
    __shared__ int cnt[NBMAX];               // 6.3 KB
    __shared__ int s[256];
    __shared__ int carry;
    const int tid = threadIdx.x;

    // fused xcvt
    for (int i = blockIdx.x * blockDim.x + tid; i < n4; i += gridDim.x * blockDim.x) {
        const float4 v = x[i];
        ushort4 o;
        o.x = (unsigned short)f2b(v.x);
        o.y = (unsigned short)f2b(v.y);
        o.z = (unsigned short)f2b(v.z);
        o.w = (unsigned short)f2b(v.w);
        x16[i] = o;
    }

    const int e0 = blockIdx.x * C;
    const int e1 = min(e0 + C, E);

    for (int i = tid; i < NB; i += 256) cnt[i] = 0;
    if (tid == 0) carry = 0;
    __syncthreads();

    for (int i = e0 + tid; i < e1; i += 256) {
        const int dst = __builtin_nontemporal_load(&ei[E + i]);
        atomicAdd(&cnt[dst >> 6], 1);
    }
    __syncthreads();

    for (int base = 0; base < NB; base += 256) {
        const int i = base + tid;
        const int v = (i < NB) ? cnt[i] : 0;
        s[tid] = v;
        __syncthreads();
        for (int d = 1; d < 256; d <<= 1) {
            const int u = (tid >= d) ? s[tid - d] : 0;
            __syncthreads();
            s[tid] += u;
            __syncthreads();
        }
        const int c0 = carry;
        const int excl = c0 + s[tid] - v;
        if (i < NB) {
            tab[(size_t)blockIdx.x * NB + i] = ((unsigned int)excl << 16) | (unsigned int)v;
            cnt[i] = excl;
        }
        __syncthreads();
        if (tid == 0) carry = c0 + s[255];
        __syncthreads();
    }

    for (int i = e0 + tid; i < e1; i += 256) {
        const int dst = __builtin_nontemporal_load(&ei[E + i]);
        const int src = __builtin_nontemporal_load(&ei[i]);
        const f32x4 a = __builtin_nontemporal_load((const f32x4*)&ea[(size_t)i * 4]);
        const int p = atomicAdd(&cnt[dst >> 6], 1);
        srec[3 * p + 0] = (unsigned int)src | ((unsigned int)(dst & 63) << 20);
        srec[3 * p + 1] = f2b(a.x) | (f2b(a.y) << 16);
        srec[3 * p + 2] = f2b(a.z) | (f2b(a.w) << 16);
    }
    __syncthreads();

    const int nd = 3 * (e1 - e0);
    unsigned int* qb = queue + (size_t)blockIdx.x * 3 * C;
    for (int d = tid; d < nd; d += 256) qb[d] = srec[d];
}

// =====================  transpose tab[NCHUNK][NB] -> tabT[NB][NCHUNK]  ==============
__global__ __launch_bounds__(256) void transp_kernel(const unsigned int* __restrict__ tab,
                                                     unsigned int* __restrict__ tabT, int NB) {
    __shared__ unsigned int tile[32][33];
    const int tx = threadIdx.x & 31;
    const int ty = threadIdx.x >> 5;  // 0..7
    const int bx = blockIdx.x * 32;   // NB dim
    const int by = blockIdx.y * 32;   // NCHUNK dim
    for (int r = ty; r < 32; r += 8) {
        const int c = bx + tx;
        tile[r][tx] = (c < NB) ? tab[(size_t)(by + r) * NB + c] : 0u;
    }
    __syncthreads();
    for (int r = ty; r < 32; r += 8) {
        const int ob = bx + r;
        if (ob < NB) tabT[(size_t)ob * NCHUNK + by + tx] = tile[tx][r];
    }
}

// =====================  bgather (512 threads): stage + index sort + gather  ========
__global__ __launch_bounds__(512) void bgather_kernel(
    const float* __restrict__ x, const unsigned short* __restrict__ x16,
    const unsigned int* __restrict__ queue, const unsigned int* __restrict__ tabT,
    const float* __restrict__ We, const float* __restrict__ be,
    float* __restrict__ hout, int N, int C) {
    __shared__ unsigned int srec[3 * CAP];   // 18 KB
    __shared__ unsigned short sidx[CAP];     // 3 KB (premultiplied by 3)
    __shared__ unsigned int ltab[NCHUNK];    // 2 KB
    __shared__ int soff[NCHUNK];             // 2 KB
    __shared__ int bins[64], boff[64], bcur[64];
    __shared__ int wtot[8], wexc[8];
    __shared__ int totB;
    const int tid = threadIdx.x;
    const int lane = tid & 63;
    const int w = tid >> 6;  // 0..7
    const int b = blockIdx.x;

    const unsigned int pw01 = f2b(We[lane]) | (f2b(We[64 + lane]) << 16);
    const unsigned int pw23 = f2b(We[128 + lane]) | (f2b(We[192 + lane]) << 16);
    const float bb = be[lane];

    const unsigned int u = tabT[(size_t)b * NCHUNK + tid];
    ltab[tid] = u;
    if (tid < 64) bins[tid] = 0;

    // hierarchical scan of run lengths
    const int v = (int)(u & 0xFFFFu);
    int incl = v;
#pragma unroll
    for (int d = 1; d < 64; d <<= 1) {
        const int up = __shfl_up(incl, d);
        if (lane >= d) incl += up;
    }
    if (lane == 63) wtot[w] = incl;
    __syncthreads();
    if (tid < 8) {
        const int mine = wtot[tid];
        int wi = mine;
#pragma unroll
        for (int d = 1; d < 8; d <<= 1) {
            const int up = __shfl_up(wi, d);
            if (tid >= d) wi += up;
        }
        wexc[tid] = wi - mine;
        if (tid == 7) totB = wi;
    }
    __syncthreads();
    const int sp = wexc[w] + incl - v;
    soff[tid] = sp;
    const int cntB = totB;

    // stage: one run per thread
    {
        const unsigned int* qp = queue + (size_t)tid * 3 * C + 3 * (size_t)(u >> 16);
        for (int k = 0; k < v; ++k) {
            const int p = sp + k;
            if (p >= CAP) break;
            const unsigned int r0 = qp[3 * k + 0];
            srec[3 * p + 0] = r0;
            srec[3 * p + 1] = qp[3 * k + 1];
            srec[3 * p + 2] = qp[3 * k + 2];
            atomicAdd(&bins[(r0 >> 20) & 63], 1);
        }
    }
    __syncthreads();

    // 64-bin exclusive scan (wave 0)
    if (tid < 64) {
        const int mine = bins[tid];
        int bi = mine;
#pragma unroll
        for (int d = 1; d < 64; d <<= 1) {
            const int up = __shfl_up(bi, d);
            if (tid >= d) bi += up;
        }
        boff[tid] = bi - mine;
        bcur[tid] = bi - mine;
    }
    __syncthreads();

    // place premultiplied indices
    const int nst = min(cntB, CAP);
    for (int i = tid; i < nst; i += 512) {
        const int dl = (int)((srec[3 * i] >> 20) & 63u);
        const int p = atomicAdd(&bcur[dl], 1);
        sidx[p] = (unsigned short)(3 * i);
    }
    __syncthreads();

    // gather: wave w handles nodes d = w + 8*j; 8-way unrolled edge loop for MLP
    for (int j = 0; j < 8; ++j) {
        const int d = w + 8 * j;
        const int n = b * 64 + d;
        if (n >= N) continue;
        const int s0 = boff[d];
        const int cnt = bins[d];
        float acc = x[(size_t)n * HIDDEN + lane];
        int k = 0;
        for (; k + 8 <= cnt; k += 8) {
            int ii[8];
#pragma unroll
            for (int q = 0; q < 8; ++q) ii[q] = sidx[s0 + k + q];
            unsigned int aa[8], yy[8], zz[8];
#pragma unroll
            for (int q = 0; q < 8; ++q) {
                aa[q] = srec[ii[q]];
                yy[q] = srec[ii[q] + 1];
                zz[q] = srec[ii[q] + 2];
            }
            float xv[8];
#pragma unroll
            for (int q = 0; q < 8; ++q)
                xv[q] = b2f(x16[(size_t)(aa[q] & 0xFFFFFu) * HIDDEN + lane]);
#pragma unroll
            for (int q = 0; q < 8; ++q)
                acc += fmaxf(dot2b(yy[q], pw01, dot2b(zz[q], pw23, bb + xv[q])), 0.0f);
        }
        for (; k + 4 <= cnt; k += 4) {
            const int i0 = sidx[s0 + k + 0];
            const int i1 = sidx[s0 + k + 1];
            const int i2 = sidx[s0 + k + 2];
            const int i3 = sidx[s0 + k + 3];
            const unsigned int a0 = srec[i0], y0 = srec[i0 + 1], z0 = srec[i0 + 2];
            const unsigned int a1 = srec[i1], y1 = srec[i1 + 1], z1 = srec[i1 + 2];
            const unsigned int a2 = srec[i2], y2 = srec[i2 + 1], z2 = srec[i2 + 2];
            const unsigned int a3 = srec[i3], y3 = srec[i3 + 1], z3 = srec[i3 + 2];
            const float x0 = b2f(x16[(size_t)(a0 & 0xFFFFFu) * HIDDEN + lane]);
            const float x1 = b2f(x16[(size_t)(a1 & 0xFFFFFu) * HIDDEN + lane]);
            const float x2 = b2f(x16[(size_t)(a2 & 0xFFFFFu) * HIDDEN + lane]);
            const float x3 = b2f(x16[(size_t)(a3 & 0xFFFFFu) * HIDDEN + lane]);
            acc += fmaxf(dot2b(y0, pw01, dot2b(z0, pw23, bb + x0)), 0.0f);
            acc += fmaxf(dot2b(y1, pw01, dot2b(z1, pw23, bb + x1)), 0.0f);
            acc += fmaxf(dot2b(y2, pw01, dot2b(z2, pw23, bb + x2)), 0.0f);
            acc += fmaxf(dot2b(y3, pw01, dot2b(z3, pw23, bb + x3)), 0.0f);
        }
        for (; k < cnt; ++k) {
            const int i0 = sidx[s0 + k];
            const unsigned int a0 = srec[i0], y0 = srec[i0 + 1], z0 = srec[i0 + 2];
            const float xv = b2f(x16[(size_t)(a0 & 0xFFFFFu) * HIDDEN + lane]);
            acc += fmaxf(dot2b(y0, pw01, dot2b(z0, pw23, bb + xv)), 0.0f);
        }
        // overflow (cntB > CAP): astronomically rare, correct-slow path
        if (cntB > CAP) {
            for (int c = 0; c < NCHUNK; ++c) {
                const unsigned int uu = ltab[c];
                const int cntc = (int)(uu & 0xFFFFu);
                const int spc = soff[c];
                int kst = CAP - spc;
                if (kst < 0) kst = 0;
                if (kst >= cntc) continue;
                const unsigned int* qp = queue + (size_t)c * 3 * C + 3 * (size_t)(uu >> 16);
                for (int kk = kst; kk < cntc; ++kk) {
                    const unsigned int a0 = qp[3 * kk];
                    if ((int)((a0 >> 20) & 63u) != d) continue;
                    const unsigned int y0 = qp[3 * kk + 1], z0 = qp[3 * kk + 2];
                    const float xv = b2f(x16[(size_t)(a0 & 0xFFFFFu) * HIDDEN + lane]);
                    acc += fmaxf(dot2b(y0, pw01, dot2b(z0, pw23, bb + xv)), 0.0f);
                }
            }
        }
        hout[(size_t)n * HIDDEN + lane] = acc;
    }
}

// =====================  MLP via MFMA (LDS-staged W, grid-stride; verified)  =========
__global__ __launch_bounds__(256) void mlp_mfma_kernel(float* __restrict__ hio,
                                                       const float* __restrict__ W1,
                                                       const float* __restrict__ b1,
                                                       const float* __restrict__ W2,
                                                       const float* __restrict__ b2, int N) {
    __shared__ unsigned short w1s[4096], w2s[4096];
    __shared__ unsigned short tlds[4][16 * 72];
    const int tid = threadIdx.x;
    const int lane = tid & 63;
    const int wid = tid >> 6;
    const int g = lane >> 4;
    const int c = lane & 15;

    for (int i = tid; i < 4096; i += 256) {
        w1s[i] = (unsigned short)f2b(W1[i]);
        w2s[i] = (unsigned short)f2b(W2[i]);
    }
    __syncthreads();

    U8 a1[4][2], a2[4][2];
#pragma unroll
    for (int ct = 0; ct < 4; ++ct)
#pragma unroll
        for (int kk = 0; kk < 2; ++kk)
#pragma unroll
            for (int j = 0; j < 8; ++j) {
                a1[ct][kk].s[j] = w1s[(kk * 32 + g * 8 + j) * 64 + ct * 16 + c];
                a2[ct][kk].s[j] = w2s[(kk * 32 + g * 8 + j) * 64 + ct * 16 + c];
            }
    float b1c[4][4], b2c[4][4];
#pragma unroll
    for (int ct = 0; ct < 4; ++ct)
#pragma unroll
        for (int r = 0; r < 4; ++r) {
            b1c[ct][r] = b1[ct * 16 + g * 4 + r];
            b2c[ct][r] = b2[ct * 16 + g * 4 + r];
        }

    unsigned char* myb = (unsigned char*)&tlds[wid][0];
    const int ntiles = (N + 15) >> 4;

    for (int tile = blockIdx.x * 4 + wid; tile < ntiles; tile += gridDim.x * 4) {
        const int row = tile * 16 + c;
        const int rowc = min(row, N - 1);

        U8 b1f[2];
#pragma unroll
        for (int kk = 0; kk < 2; ++kk) {
            const float4* hp = (const float4*)&hio[(size_t)rowc * 64 + kk * 32 + g * 8];
            const float4 lo = hp[0];
            const float4 hi = hp[1];
            b1f[kk].d[0] = f2b(lo.x) | (f2b(lo.y) << 16);
            b1f[kk].d[1] = f2b(lo.z) | (f2b(lo.w) << 16);
            b1f[kk].d[2] = f2b(hi.x) | (f2b(hi.y) << 16);
            b1f[kk].d[3] = f2b(hi.z) | (f2b(hi.w) << 16);
        }
        f32x4 acc1[4];
#pragma unroll
        for (int ct = 0; ct < 4; ++ct) {
            acc1[ct] = (f32x4)(0.0f);
#pragma unroll
            for (int kk = 0; kk < 2; ++kk)
                acc1[ct] = __builtin_amdgcn_mfma_f32_16x16x32_bf16(a1[ct][kk].v, b1f[kk].v,
                                                                   acc1[ct], 0, 0, 0);
        }
#pragma unroll
        for (int ct = 0; ct < 4; ++ct)
#pragma unroll
            for (int rp = 0; rp < 2; ++rp) {
                const float v0 = fmaxf(acc1[ct][2 * rp + 0] + b1c[ct][2 * rp + 0], 0.0f);
                const float v1 = fmaxf(acc1[ct][2 * rp + 1] + b1c[ct][2 * rp + 1], 0.0f);
                *(unsigned int*)(myb + c * 144 + ct * 32 + g * 8 + rp * 4) =
                    f2b(v0) | (f2b(v1) << 16);
            }
        U8 b2f_[2];
#pragma unroll
        for (int kk2 = 0; kk2 < 2; ++kk2) {
            const unsigned int* q = (const unsigned int*)(myb + c * 144 + kk2 * 64 + g * 16);
            b2f_[kk2].d[0] = q[0];
            b2f_[kk2].d[1] = q[1];
            b2f_[kk2].d[2] = q[2];
            b2f_[kk2].d[3] = q[3];
        }
        f32x4 acc2[4];
#pragma unroll
        for (int ct = 0; ct < 4; ++ct) {
            acc2[ct] = (f32x4)(0.0f);
#pragma unroll
            for (int kk2 = 0; kk2 < 2; ++kk2)
                acc2[ct] = __builtin_amdgcn_mfma_f32_16x16x32_bf16(a2[ct][kk2].v, b2f_[kk2].v,
                                                                   acc2[ct], 0, 0, 0);
        }
        if (row < N) {
#pragma unroll
            for (int ct = 0; ct < 4; ++ct)
#pragma unroll
                for (int r = 0; r < 4; ++r)
                    hio[(size_t)row * 64 + ct * 16 + g * 4 + r] = acc2[ct][r] + b2c[ct][r];
        }
    }
}

// =====================  fallback path (ws too small / params out of range)  =========
__global__ __launch_bounds__(256) void mlp_kernel(const float* __restrict__ hin,
                                                  const float* __restrict__ W1,
                                                  const float* __restrict__ b1,
                                                  const float* __restrict__ W2,
                                                  const float* __restrict__ b2,
                                                  float* __restrict__ out, int N) {
    const int lane = threadIdx.x & 63;
    float w1c[64], w2c[64];
#pragma unroll
    for (int k = 0; k < 64; ++k) w1c[k] = W1[k * 64 + lane];
#pragma unroll
    for (int k = 0; k < 64; ++k) w2c[k] = W2[k * 64 + lane];
    const float bb1 = b1[lane];
    const float bb2 = b2[lane];
    int wave = (blockIdx.x * blockDim.x + threadIdx.x) >> 6;
    const int nw = (gridDim.x * blockDim.x) >> 6;
    for (int n = wave; n < N; n += nw) {
        const float h = hin[(size_t)n * HIDDEN + lane];
        float t0 = bb1, t1 = 0.0f;
#pragma unroll
        for (int k = 0; k < 64; k += 2) {
            t0 = fmaf(lane_bcast(h, k), w1c[k], t0);
            t1 = fmaf(lane_bcast(h, k + 1), w1c[k + 1], t1);
        }
        const float t = fmaxf(t0 + t1, 0.0f);
        float o0 = bb2, o1 = 0.0f;
#pragma unroll
        for (int k = 0; k < 64; k += 2) {
            o0 = fmaf(lane_bcast(t, k), w2c[k], o0);
            o1 = fmaf(lane_bcast(t, k + 1), w2c[k + 1], o1);
        }
        out[(size_t)n * HIDDEN + lane] = o0 + o1;
    }
}

__global__ __launch_bounds__(256) void gine_copy_kernel(const float4* __restrict__ x,
                                                        float4* __restrict__ out, int n4) {
    int i = blockIdx.x * blockDim.x + threadIdx.x;
    int stride = gridDim.x * blockDim.x;
    for (; i < n4; i += stride) out[i] = x[i];
}

__global__ __launch_bounds__(256) void gine_edge_kernel(const float* __restrict__ x,
                                                        const int* __restrict__ ei,
                                                        const float4* __restrict__ ea,
                                                        const float* __restrict__ We,
                                                        const float* __restrict__ be,
                                                        float* __restrict__ out, int E) {
    const int lane = threadIdx.x & 63;
    const float w0 = We[lane];
    const float w1 = We[64 + lane];
    const float w2 = We[128 + lane];
    const float w3 = We[192 + lane];
    const float bb = be[lane];
    int wave = (blockIdx.x * blockDim.x + threadIdx.x) >> 6;
    const int nw = (gridDim.x * blockDim.x) >> 6;
    for (int e = wave; e < E; e += nw) {
        const int src = ei[e];
        const int dst = ei[E + e];
        const float4 a = ea[e];
        float m = x[src * HIDDEN + lane] + (bb + a.x * w0 + a.y * w1 + a.z * w2 + a.w * w3);
        m = fmaxf(m, 0.0f);
        atomicAdd(out + dst * HIDDEN + lane, m);
    }
}

extern "C" void kernel_launch(void* const* d_in, const int* in_sizes, int n_in,
                              void* d_out, int out_size, void* d_ws, size_t ws_size,
                              hipStream_t stream) {
    const float* x  = (const float*)d_in[0];
    const int*   ei = (const int*)d_in[1];
    const float* ea = (const float*)d_in[2];
    const float* We = (const float*)d_in[3];
    const float* be = (const float*)d_in[4];
    const float* W1 = (const float*)d_in[5];
    const float* b1 = (const float*)d_in[6];
    const float* W2 = (const float*)d_in[7];
    const float* b2 = (const float*)d_in[8];
    float* out = (float*)d_out;

    const int N = in_sizes[0] / HIDDEN;  // 100000
    const int E = in_sizes[1] / 2;       // 1600000
    const int C = (E + NCHUNK - 1) / NCHUNK;  // 3125
    const int NB = (N + 63) >> 6;             // 1563

    // Workspace layout
    size_t p = 0;
    const size_t x16_ofs  = p; p += ((size_t)N * HIDDEN * 2 + 255) & ~(size_t)255;
    const size_t q_ofs    = p; p += ((size_t)NCHUNK * 3 * C * 4 + 255) & ~(size_t)255;
    const size_t tab_ofs  = p; p += ((size_t)NCHUNK * NB * 4 + 255) & ~(size_t)255;
    const size_t tabT_ofs = p; p += ((size_t)NB * NCHUNK * 4 + 255) & ~(size_t)255;
    const size_t need = p;

    const bool ok = (ws_size >= need) && (NB <= NBMAX) && (C <= CMAX) && (N <= (1 << 20));
    if (!ok) {
        gine_copy_kernel<<<2048, 256, 0, stream>>>((const float4*)x, (float4*)out,
                                                   N * (HIDDEN / 4));
        gine_edge_kernel<<<2048, 256, 0, stream>>>(x, ei, (const float4*)ea, We, be, out, E);
        mlp_kernel<<<2048, 256, 0, stream>>>(out, W1, b1, W2, b2, out, N);
        return;
    }

    char* ws = (char*)d_ws;
    unsigned short* x16   = (unsigned short*)(ws + x16_ofs);
    unsigned int*   queue = (unsigned int*)(ws + q_ofs);
    unsigned int*   tab   = (unsigned int*)(ws + tab_ofs);
    unsigned int*   tabT  = (unsigned int*)(ws + tabT_ofs);

    qsort_kernel<<<NCHUNK, 256, 0, stream>>>((const float4*)x, (ushort4*)x16,
                                             N * (HIDDEN / 4), ei, ea, queue, tab, E, C, NB);
    dim3 tgrid((NB + 31) / 32, NCHUNK / 32);
    transp_kernel<<<tgrid, 256, 0, stream>>>(tab, tabT, NB);
    bgather_kernel<<<NB, 512, 0, stream>>>(x, x16, queue, tabT, We, be, out, N, C);
    mlp_mfma_kernel<<<640, 256, 0, stream>>>(out, W1, b1, W2, b2, N);
}